// Round 15
// baseline (812.294 us; speedup 1.0000x reference)
//
#include <hip/hip_runtime.h>

#define NB 8   // batch
#define TT 64  // time

typedef __attribute__((ext_vector_type(8))) short bf16x8_t;
typedef __attribute__((ext_vector_type(4))) float f32x4_t;

__device__ __forceinline__ float sigm(float x){ return 1.0f/(1.0f+expf(-x)); }
__device__ __forceinline__ float eluf(float x){ return x>0.0f ? x : expm1f(x); }
__device__ __forceinline__ ushort f2bf(float f){
  uint u = __float_as_uint(f);
  return (ushort)((u + 0x7FFFu + ((u >> 16) & 1u)) >> 16);   // RNE
}
__device__ __forceinline__ float bf2f(ushort u){
  return __uint_as_float(((uint)u) << 16);
}

// CSR fused-level geometry (levels 0..3)
__device__ __constant__ int c_VL[4] = {2048, 1024, 512, 256};
__device__ __constant__ int c_VO[4] = {0, 2048, 3072, 3584};
__device__ __constant__ int c_EO[4] = {0, 12288, 18432, 21504};
#define TOTV 3840
#define TOTE 23040

// ---------------- small utilities ----------------
__global__ void transpose_kernel(const float* __restrict__ in, float* __restrict__ out, int R, int C){
  int idx = blockIdx.x*256 + threadIdx.x;
  if (idx >= R*C) return;
  int r = idx / C, c = idx - r*C;
  out[c*R + r] = in[idx];
}

__global__ void conv_bf16(const float* __restrict__ in, ushort* __restrict__ out, int n){
  int i = blockIdx.x*256 + threadIdx.x;
  if (i < n) out[i] = f2bf(in[i]);
}

// (192,64) fp32 -> (256,64) bf16, zero-padded rows
__global__ void pad_wih(const float* __restrict__ in, ushort* __restrict__ out){
  int i = blockIdx.x*256 + threadIdx.x;
  if (i >= 256*64) return;
  int r = i >> 6;
  out[i] = (r < 192) ? f2bf(in[i]) : (ushort)0;
}

// transpose+convert: in (NB, R, C) fp32 -> out (NB, C, R) bf16  (for pool BT)
__global__ __launch_bounds__(256) void transp_bf16(
    const float* __restrict__ in, ushort* __restrict__ out, int R, int Ccols){
  __shared__ float tile[64][65];
  int n = blockIdx.z;
  const float* ip = in + (size_t)n*R*Ccols;
  ushort* op = out + (size_t)n*R*Ccols;
  int tid = threadIdx.x;
  int tx = tid & 63, ty = tid >> 6;
  int r0 = blockIdx.y*64, c0 = blockIdx.x*64;
  #pragma unroll
  for (int i = 0; i < 64; i += 4)
    tile[ty+i][tx] = ip[(size_t)(r0+ty+i)*Ccols + c0 + tx];
  __syncthreads();
  #pragma unroll
  for (int i = 0; i < 64; i += 4)
    op[(size_t)(c0+ty+i)*R + r0 + tx] = f2bf(tile[tx][ty+i]);
}

// per-vertex activation transpose: in (S, Ci, 64) fp32 -> out (S, 64, CiP) bf16, zero-pad ci>=Ci
template<int Ci, int CiP>
__global__ __launch_bounds__(256) void xpose_bf16(const float* __restrict__ in, ushort* __restrict__ out){
  __shared__ float tile[Ci][65];
  int s = blockIdx.x, tid = threadIdx.x;
  const float* ip = in + (size_t)s*Ci*64;
  for (int i = tid; i < Ci*64; i += 256) tile[i>>6][i&63] = ip[i];
  __syncthreads();
  ushort* op = out + (size_t)s*64*CiP;
  for (int i = tid; i < 64*CiP; i += 256){
    int t = i / CiP, ci = i - t*CiP;
    op[i] = (ci < Ci) ? f2bf(tile[ci][t]) : (ushort)0;
  }
}

// ---------------- parallel CSR build ----------------
__global__ void csr_zero(int* __restrict__ deg_all){
  int i = blockIdx.x*256 + threadIdx.x;
  if (i < TOTV) deg_all[i] = 0;
}

__global__ void csr_deg(const int* __restrict__ d0, const int* __restrict__ d1,
                        const int* __restrict__ d2, const int* __restrict__ d3,
                        int* __restrict__ deg_all){
  int idx = blockIdx.x*256 + threadIdx.x;
  if (idx >= TOTE) return;
  int l = (idx < 12288) ? 0 : (idx < 18432) ? 1 : (idx < 21504) ? 2 : 3;
  int e = idx - c_EO[l];
  const int* dl = (l==0)?d0:(l==1)?d1:(l==2)?d2:d3;
  atomicAdd(&deg_all[c_VO[l] + dl[e]], 1);
}

__global__ __launch_bounds__(1024) void csr_scan(const int* __restrict__ deg_all,
                                                 int* __restrict__ rowptr_all,
                                                 int* __restrict__ cursor_all){
  __shared__ int a[2048], b[2048];
  int l = blockIdx.x;
  int Vv = c_VL[l], vo = c_VO[l], eo = c_EO[l];
  int tid = threadIdx.x;
  for (int i = tid; i < 2048; i += 1024) a[i] = (i < Vv) ? deg_all[vo + i] : 0;
  __syncthreads();
  int* s = a; int* d = b;
  for (int off = 1; off < 2048; off <<= 1){
    for (int i = tid; i < 2048; i += 1024) d[i] = s[i] + ((i >= off) ? s[i-off] : 0);
    __syncthreads();
    int* t = s; s = d; d = t;
  }
  int rbase = vo + l;
  for (int i = tid; i < Vv; i += 1024){
    int excl = (i == 0) ? 0 : s[i-1];
    rowptr_all[rbase + i] = excl;
    cursor_all[vo + i]    = eo + excl;
  }
  if (tid == 0) rowptr_all[rbase + Vv] = s[2047];
}

__global__ void csr_fill(const int* __restrict__ d0, const int* __restrict__ d1,
                         const int* __restrict__ d2, const int* __restrict__ d3,
                         int* __restrict__ cursor_all, int* __restrict__ elist_all){
  int idx = blockIdx.x*256 + threadIdx.x;
  if (idx >= TOTE) return;
  int l = (idx < 12288) ? 0 : (idx < 18432) ? 1 : (idx < 21504) ? 2 : 3;
  int e = idx - c_EO[l];
  const int* dl = (l==0)?d0:(l==1)?d1:(l==2)?d2:d3;
  int p = atomicAdd(&cursor_all[c_VO[l] + dl[e]], 1);
  elist_all[p] = e;
}

__global__ void csr_sort(const int* __restrict__ rowptr_all, int* __restrict__ elist_all){
  int idx = blockIdx.x*256 + threadIdx.x;
  if (idx >= TOTV) return;
  int l = (idx < 2048) ? 0 : (idx < 3072) ? 1 : (idx < 3584) ? 2 : 3;
  int v = idx - c_VO[l];
  int rbase = c_VO[l] + l, eo = c_EO[l];
  int s = eo + rowptr_all[rbase + v], epos = eo + rowptr_all[rbase + v + 1];
  for (int i = s + 1; i < epos; ++i){
    int key = elist_all[i];
    int j = i - 1;
    while (j >= s && elist_all[j] > key){ elist_all[j+1] = elist_all[j]; --j; }
    elist_all[j+1] = key;
  }
}

// B-spline edge weights (fp32, for vector gconv levels 0/1)
__global__ void edge_we_kernel(const float* __restrict__ attr, const float* __restrict__ Wb,
                               float* __restrict__ We, int E, int CiCo){
  int idx = blockIdx.x*256 + threadIdx.x;
  if (idx >= E*CiCo) return;
  int e = idx / CiCo, r = idx - e*CiCo;
  float f[3]; int i0[3];
  #pragma unroll
  for (int d = 0; d < 3; ++d){
    float p  = attr[e*3+d]*2.0f;
    float fl = fminf(fmaxf(floorf(p), 0.0f), 1.0f);
    i0[d] = (int)fl;
    f[d]  = p - fl;
  }
  float acc = 0.0f;
  #pragma unroll
  for (int c0 = 0; c0 < 2; ++c0){
    float w0 = c0 ? f[0] : 1.0f - f[0];
    #pragma unroll
    for (int c1 = 0; c1 < 2; ++c1){
      float w1 = c1 ? f[1] : 1.0f - f[1];
      #pragma unroll
      for (int c2 = 0; c2 < 2; ++c2){
        float w2 = c2 ? f[2] : 1.0f - f[2];
        int flat = (i0[0]+c0)*9 + (i0[1]+c1)*3 + (i0[2]+c2);
        acc += w0*w1*w2 * Wb[flat*CiCo + r];
      }
    }
  }
  We[idx] = acc;
}

// B-spline -> transposed bf16 WeT[e, co, ciP]: block-per-edge, coalesced reads, LDS transpose
template<int Ci, int Co, int CiP>
__global__ __launch_bounds__(256) void edge_weT2(
    const float* __restrict__ attr, const float* __restrict__ Wb,
    ushort* __restrict__ WeT){
  __shared__ float s[Ci][Co + 1];
  int e = blockIdx.x, tid = threadIdx.x;
  float f[3]; int i0[3];
  #pragma unroll
  for (int d = 0; d < 3; ++d){
    float p  = attr[e*3+d]*2.0f;
    float fl = fminf(fmaxf(floorf(p), 0.0f), 1.0f);
    i0[d] = (int)fl;
    f[d]  = p - fl;
  }
  float w[8]; int fl8[8];
  #pragma unroll
  for (int c0 = 0; c0 < 2; ++c0)
    #pragma unroll
    for (int c1 = 0; c1 < 2; ++c1)
      #pragma unroll
      for (int c2 = 0; c2 < 2; ++c2){
        int k = c0*4 + c1*2 + c2;
        w[k] = (c0 ? f[0] : 1.0f - f[0]) * (c1 ? f[1] : 1.0f - f[1]) * (c2 ? f[2] : 1.0f - f[2]);
        fl8[k] = (i0[0]+c0)*9 + (i0[1]+c1)*3 + (i0[2]+c2);
      }
  constexpr int CiCo = Ci*Co;
  for (int r = tid; r < CiCo; r += 256){
    float acc = 0.0f;
    #pragma unroll
    for (int k = 0; k < 8; ++k) acc += w[k]*Wb[fl8[k]*CiCo + r];
    s[r/Co][r - (r/Co)*Co] = acc;
  }
  __syncthreads();
  ushort* op = WeT + (size_t)e*(Co*CiP);
  for (int r2 = tid; r2 < Co*CiP; r2 += 256){
    int co = r2 / CiP, ci = r2 - co*CiP;
    op[r2] = (ci < Ci) ? f2bf(s[ci][co]) : (ushort)0;
  }
}

// ---------------- graph conv (vector path, levels 0/1) ----------------
template<int Ci, int Co>
__global__ __launch_bounds__(256) void gconv2_kernel(
    const float* __restrict__ x, const float* __restrict__ We,
    const int* __restrict__ src_arr, const int* __restrict__ rowptr,
    const int* __restrict__ elist, float* __restrict__ out, int V){
  constexpr int CiCo = Ci*Co;
  __shared__ float ws[4][CiCo];
  __shared__ float red[Co*64];
  int blk = blockIdx.x;
  int n = blk / V, v = blk - n*V;
  int tid = threadIdx.x;
  int w = tid >> 6, lane = tid & 63;
  int rs = rowptr[v], re = rowptr[v+1];
  float acc[Co];
  #pragma unroll
  for (int i = 0; i < Co; ++i) acc[i] = 0.0f;

  for (int q = rs + w; q < re; q += 4){
    int e   = elist[q];
    int src = src_arr[e];
    const float* wsrc = We + (size_t)e*CiCo;
    #pragma unroll
    for (int i = lane; i < CiCo; i += 64) ws[w][i] = wsrc[i];
    __builtin_amdgcn_s_waitcnt(0);
    const float* xp = x + ((size_t)(n*V + src))*(Ci*64) + lane;
    #pragma unroll 4
    for (int ci = 0; ci < Ci; ++ci){
      float xv = xp[(size_t)ci*64];
      if constexpr (Co >= 4){
        #pragma unroll
        for (int co = 0; co < Co; co += 4){
          float4 wv = *(const float4*)&ws[w][ci*Co + co];
          acc[co+0] += wv.x*xv;
          acc[co+1] += wv.y*xv;
          acc[co+2] += wv.z*xv;
          acc[co+3] += wv.w*xv;
        }
      } else {
        #pragma unroll
        for (int co = 0; co < Co; ++co) acc[co] += ws[w][ci*Co + co]*xv;
      }
    }
  }

  if (w == 0){
    #pragma unroll
    for (int co = 0; co < Co; ++co) red[co*64 + lane] = acc[co];
  }
  __syncthreads();
  #pragma unroll
  for (int ww = 1; ww < 4; ++ww){
    if (w == ww){
      #pragma unroll
      for (int co = 0; co < Co; ++co) red[co*64 + lane] += acc[co];
    }
    __syncthreads();
  }
  float scale = 1.0f / fmaxf((float)(re - rs), 1.0f);
  size_t ob = ((size_t)(n*V + v))*(Co*64);
  for (int co = w; co < Co; co += 4)
    out[ob + (size_t)co*64 + lane] = eluf(red[co*64 + lane]*scale);
}

// ---------------- graph conv (MFMA path, levels 2/3), wave-split edges, XCD-coherent ----------------
// bid remap: all 8 batch instances of a vertex share bid%8 -> same XCD -> WeT L2 reuse
template<int CiP, int Co>
__global__ __launch_bounds__(256, 4) void gconv_mfma4(
    const ushort* __restrict__ xT, const ushort* __restrict__ WeT,
    const int* __restrict__ src_arr, const int* __restrict__ rowptr,
    const int* __restrict__ elist, float* __restrict__ out, int V){
  constexpr int MT = Co/16, KT = CiP/32;
  __shared__ int2 es[64];
  __shared__ float red[Co*64];
  int bid = blockIdx.x;
  int r8 = bid & 7, q0 = bid >> 3;
  int n = q0 & 7;                 // NB = 8
  int v = ((q0 >> 3) << 3) | r8;  // V multiple of 8
  int tid = threadIdx.x;
  int w = tid >> 6, lane = tid & 63;
  int l15 = lane & 15, g = lane >> 4;
  int rs = rowptr[v], re = rowptr[v+1];
  int deg = re - rs;
  int cnt0 = (deg < 64) ? deg : 64;
  if (tid < cnt0){
    int e = elist[rs + tid];
    es[tid] = make_int2(e, src_arr[e]);
  }
  __syncthreads();
  f32x4_t acc[MT][4];
  #pragma unroll
  for (int m = 0; m < MT; ++m)
    #pragma unroll
    for (int tt = 0; tt < 4; ++tt) acc[m][tt] = (f32x4_t){0.f,0.f,0.f,0.f};
  for (int q = w; q < deg; q += 4){
    int e, src;
    if (q < 64){ e = es[q].x; src = es[q].y; }
    else { e = elist[rs + q]; src = src_arr[e]; }
    const ushort* xp = xT + ((size_t)(n*V + src))*(64*CiP) + (size_t)l15*CiP + g*8;
    const ushort* wp = WeT + (size_t)e*(Co*CiP) + (size_t)l15*CiP + g*8;
    #pragma unroll
    for (int kt = 0; kt < KT; ++kt){
      bf16x8_t bfrag[4];
      #pragma unroll
      for (int tt = 0; tt < 4; ++tt)
        bfrag[tt] = *(const bf16x8_t*)(xp + (size_t)tt*16*CiP + kt*32);
      #pragma unroll
      for (int m = 0; m < MT; ++m){
        bf16x8_t afrag = *(const bf16x8_t*)(wp + (size_t)m*16*CiP + kt*32);
        #pragma unroll
        for (int tt = 0; tt < 4; ++tt)
          acc[m][tt] = __builtin_amdgcn_mfma_f32_16x16x32_bf16(afrag, bfrag[tt], acc[m][tt], 0, 0, 0);
      }
    }
  }
  // deterministic cross-wave reduce (wave order 0,1,2,3)
  if (w == 0){
    #pragma unroll
    for (int m = 0; m < MT; ++m)
      #pragma unroll
      for (int tt = 0; tt < 4; ++tt)
        #pragma unroll
        for (int r = 0; r < 4; ++r)
          red[(m*16 + g*4 + r)*64 + tt*16 + l15] = acc[m][tt][r];
  }
  __syncthreads();
  #pragma unroll
  for (int ww = 1; ww < 4; ++ww){
    if (w == ww){
      #pragma unroll
      for (int m = 0; m < MT; ++m)
        #pragma unroll
        for (int tt = 0; tt < 4; ++tt)
          #pragma unroll
          for (int r = 0; r < 4; ++r)
            red[(m*16 + g*4 + r)*64 + tt*16 + l15] += acc[m][tt][r];
    }
    __syncthreads();
  }
  float scale = 1.0f / fmaxf((float)deg, 1.0f);
  size_t ob = ((size_t)(n*V + v))*(Co*64);
  for (int i = tid; i < Co*64; i += 256)
    out[ob + i] = eluf(red[i]*scale);
}

// ---------------- 64x64-tile MFMA GEMM: C[z] = A @ BT[z]^T ----------------
template<int OUTBF>
__global__ __launch_bounds__(256) void pool_mfma64(
    const ushort* __restrict__ A, const ushort* __restrict__ BT, void* __restrict__ Cout,
    int M, int K, int NN){
  __shared__ ushort As[64*40];
  __shared__ ushort Bs[64*40];
  char* Asb = (char*)As; char* Bsb = (char*)Bs;
  int tid = threadIdx.x;
  int wv = tid >> 6, lane = tid & 63;
  int g = lane >> 4, l15 = lane & 15;
  int wr = wv >> 1, wc = wv & 1;
  int m0 = blockIdx.y*64, n0 = blockIdx.x*64;
  const ushort* Bp = BT + (size_t)blockIdx.z*((size_t)NN*K);
  f32x4_t acc[2][2];
  #pragma unroll
  for (int i = 0; i < 2; ++i)
    #pragma unroll
    for (int j = 0; j < 2; ++j) acc[i][j] = (f32x4_t){0.f,0.f,0.f,0.f};
  int srow = tid >> 2, slot = tid & 3;
  int wbo = srow*80 + slot*16;
  const ushort* gA = A  + (size_t)(m0+srow)*K + slot*8;
  const ushort* gB = Bp + (size_t)(n0+srow)*K + slot*8;
  for (int k0 = 0; k0 < K; k0 += 32){
    uint4 va = *(const uint4*)(gA + k0);
    uint4 vb = *(const uint4*)(gB + k0);
    __syncthreads();
    *(uint4*)(Asb + wbo) = va;
    *(uint4*)(Bsb + wbo) = vb;
    __syncthreads();
    bf16x8_t af[2], bfr[2];
    #pragma unroll
    for (int f = 0; f < 2; ++f){
      af[f]  = *(const bf16x8_t*)(Asb + (wr*32 + f*16 + l15)*80 + g*16);
      bfr[f] = *(const bf16x8_t*)(Bsb + (wc*32 + f*16 + l15)*80 + g*16);
    }
    #pragma unroll
    for (int fm = 0; fm < 2; ++fm)
      #pragma unroll
      for (int fn = 0; fn < 2; ++fn)
        acc[fm][fn] = __builtin_amdgcn_mfma_f32_16x16x32_bf16(af[fm], bfr[fn], acc[fm][fn], 0, 0, 0);
  }
  #pragma unroll
  for (int fm = 0; fm < 2; ++fm){
    int row = m0 + wr*32 + fm*16 + g*4;
    #pragma unroll
    for (int fn = 0; fn < 2; ++fn){
      int col = n0 + wc*32 + fn*16 + l15;
      if constexpr (OUTBF){
        ushort* Cb = (ushort*)Cout + (size_t)blockIdx.z*((size_t)M*NN);
        #pragma unroll
        for (int r = 0; r < 4; ++r)
          Cb[(size_t)(row + r)*NN + col] = f2bf(acc[fm][fn][r]);
      } else {
        float* Cf = (float*)Cout + (size_t)blockIdx.z*((size_t)M*NN);
        #pragma unroll
        for (int r = 0; r < 4; ++r)
          Cf[(size_t)(row + r)*NN + col] = acc[fm][fn][r];
      }
    }
  }
}

// ---------------- fused dual MFMA pointwise: out = act2(W2 @ act1(W1 @ x + b1) + b2) ----------------
template<int C, int O1, int O2, int ACT1, int ACT2, int INF, int OUTF>
__global__ __launch_bounds__(256) void pw2_mfma(
    const void* __restrict__ inv,
    const ushort* __restrict__ W1, const float* __restrict__ b1,
    const ushort* __restrict__ W2, const float* __restrict__ b2,
    void* __restrict__ outv){
  constexpr int CP = C + 8, O1P = O1 + 8;
  constexpr int MT1 = O1/16, KT1 = C/32;
  constexpr int MT2 = O2/16, KT2 = O1/32;
  __shared__ ushort XT[64*CP];
  __shared__ ushort YT[64*O1P];
  int s = blockIdx.x, tid = threadIdx.x;
  int w = tid >> 6, lane = tid & 63;
  int l15 = lane & 15, g = lane >> 4;
  if constexpr (INF == 0){
    const float* ip = (const float*)inv + (size_t)s*C*64;
    for (int i = tid; i < C*64; i += 256){ int c = i >> 6, t = i & 63; XT[t*CP + c] = f2bf(ip[i]); }
  } else {
    const float* ip = (const float*)inv + (size_t)s*64*C;
    for (int i = tid; i < C*64; i += 256){ int t = i / C, c = i - t*C; XT[t*CP + c] = f2bf(ip[i]); }
  }
  __syncthreads();
  int trow = w*16 + l15;
  {
    f32x4_t acc[MT1];
    #pragma unroll
    for (int m = 0; m < MT1; ++m) acc[m] = (f32x4_t){0.f,0.f,0.f,0.f};
    #pragma unroll
    for (int kt = 0; kt < KT1; ++kt){
      bf16x8_t bfrag = *(const bf16x8_t*)(&XT[trow*CP + kt*32 + g*8]);
      #pragma unroll
      for (int m = 0; m < MT1; ++m){
        bf16x8_t afrag = *(const bf16x8_t*)(W1 + (size_t)(m*16 + l15)*C + kt*32 + g*8);
        acc[m] = __builtin_amdgcn_mfma_f32_16x16x32_bf16(afrag, bfrag, acc[m], 0, 0, 0);
      }
    }
    #pragma unroll
    for (int m = 0; m < MT1; ++m){
      #pragma unroll
      for (int r = 0; r < 4; ++r){
        int o = m*16 + g*4 + r;
        float v = acc[m][r] + b1[o];
        v = (ACT1 == 1) ? eluf(v) : tanhf(v);
        YT[trow*O1P + o] = f2bf(v);
      }
    }
  }
  __syncthreads();
  {
    f32x4_t acc[MT2];
    #pragma unroll
    for (int m = 0; m < MT2; ++m) acc[m] = (f32x4_t){0.f,0.f,0.f,0.f};
    #pragma unroll
    for (int kt = 0; kt < KT2; ++kt){
      bf16x8_t bfrag = *(const bf16x8_t*)(&YT[trow*O1P + kt*32 + g*8]);
      #pragma unroll
      for (int m = 0; m < MT2; ++m){
        bf16x8_t afrag = *(const bf16x8_t*)(W2 + (size_t)(m*16 + l15)*O1 + kt*32 + g*8);
        acc[m] = __builtin_amdgcn_mfma_f32_16x16x32_bf16(afrag, bfrag, acc[m], 0, 0, 0);
      }
    }
    if constexpr (OUTF == 0){
      float* op = (float*)outv + (size_t)s*O2*64;
      #pragma unroll
      for (int m = 0; m < MT2; ++m){
        #pragma unroll
        for (int r = 0; r < 4; ++r){
          int o = m*16 + g*4 + r;
          float v = acc[m][r] + b2[o];
          v = (ACT2 == 1) ? eluf(v) : tanhf(v);
          op[(size_t)o*64 + trow] = v;
        }
      }
    } else {
      constexpr int O2P = O2 + 8;
      #pragma unroll
      for (int m = 0; m < MT2; ++m){
        #pragma unroll
        for (int r = 0; r < 4; ++r){
          int o = m*16 + g*4 + r;
          float v = acc[m][r] + b2[o];
          v = (ACT2 == 1) ? eluf(v) : tanhf(v);
          XT[trow*O2P + o] = f2bf(v);
        }
      }
      __syncthreads();
      ushort* op = (ushort*)outv + (size_t)s*64*O2;
      for (int i = tid; i < 64*O2; i += 256){
        int t = i / O2, o = i - t*O2;
        op[i] = XT[t*O2P + o];
      }
    }
  }
}

// ---------------- merged GRU scans (dom + ini), gate-per-wave, 4-acc matvec ----------------
__global__ __launch_bounds__(192) void gru3m_kernel(
    const ushort* __restrict__ GI_d, const ushort* __restrict__ GI_i,
    const float* __restrict__ WhhT_d, const float* __restrict__ WhhT_i,
    const float* __restrict__ bih_d, const float* __restrict__ bhh_d,
    const float* __restrict__ aggT_d, const float* __restrict__ aggb_d,
    const float* __restrict__ bih_i, const float* __restrict__ bhh_i,
    const float* __restrict__ aggT_i, const float* __restrict__ aggb_i,
    float* __restrict__ zD, float* __restrict__ z0, int S){
  __shared__ float hsh[64];
  __shared__ float rbuf[64];
  __shared__ float zbuf[64];
  int bid = blockIdx.x;
  bool dom = (bid < S);
  int s = dom ? bid : bid - S;
  int TS = dom ? 64 : 16;
  const ushort* GI   = dom ? GI_d   : GI_i;
  const float* WhhT  = dom ? WhhT_d : WhhT_i;
  const float* bih   = dom ? bih_d  : bih_i;
  const float* bhh   = dom ? bhh_d  : bhh_i;
  const float* aggT  = dom ? aggT_d : aggT_i;
  const float* aggb  = dom ? aggb_d : aggb_i;
  float* zout        = dom ? zD     : z0;
  int tid = threadIdx.x;
  int g = tid >> 6, j = tid & 63;
  if (tid < 64) hsh[tid] = 0.0f;
  float whh[64];
  #pragma unroll
  for (int c = 0; c < 64; ++c) whh[c] = WhhT[c*192 + tid];
  float b_i = bih[tid], b_h = bhh[tid];
  const ushort* gp = GI + (size_t)s*64*256 + tid;
  float gi_cur = b_i + bf2f(gp[0]);
  __syncthreads();
  for (int t = 0; t < TS; ++t){
    ushort gnx = (t + 1 < TS) ? gp[(size_t)(t+1)*256] : (ushort)0;
    float g0=0.f, g1=0.f, g2=0.f, g3=0.f;
    #pragma unroll
    for (int c4 = 0; c4 < 16; ++c4){
      float4 hv = *(const float4*)&hsh[c4*4];
      g0 += whh[c4*4+0]*hv.x; g1 += whh[c4*4+1]*hv.y;
      g2 += whh[c4*4+2]*hv.z; g3 += whh[c4*4+3]*hv.w;
    }
    float gh = b_h + ((g0 + g1) + (g2 + g3));
    if (g == 0)      rbuf[j] = sigm(gi_cur + gh);
    else if (g == 1) zbuf[j] = sigm(gi_cur + gh);
    __syncthreads();
    if (g == 2){
      float gg = tanhf(gi_cur + rbuf[j]*gh);
      float z  = zbuf[j];
      hsh[j] = (1.0f - z)*gg + z*hsh[j];
    }
    __syncthreads();
    gi_cur = b_i + bf2f(gnx);
  }
  if (tid < 64){
    float a = aggb[tid];
    #pragma unroll
    for (int c = 0; c < 64; ++c) a += aggT[c*64 + tid]*hsh[c];
    zout[(size_t)s*64 + tid] = tanhf(a);
  }
}

// ---------------- transition: gate-per-wave, register weights, 4-acc matvec ----------------
__global__ __launch_bounds__(192) void trans2_kernel(
    const float* __restrict__ z0, const float* __restrict__ zD,
    const float* __restrict__ WrT, const float* __restrict__ WuT, const float* __restrict__ WcT,
    const float* __restrict__ br, const float* __restrict__ bu, const float* __restrict__ bc,
    float* __restrict__ zs){
  __shared__ float zp[64];
  __shared__ float zd[64];
  __shared__ float rz[64];
  __shared__ float ubuf[64];
  int s = blockIdx.x, tid = threadIdx.x;
  int g = tid >> 6, j = tid & 63;
  if (tid < 64){ zp[tid] = z0[(size_t)s*64 + tid]; zd[tid] = zD[(size_t)s*64 + tid]; }
  const float* WT = (g == 0) ? WrT : (g == 1) ? WuT : WcT;
  const float* bb = (g == 0) ? br  : (g == 1) ? bu  : bc;
  float wv[64];
  #pragma unroll
  for (int c = 0; c < 64; ++c) wv[c] = WT[c*64 + j];
  float bconst = bb[j];
  __syncthreads();
  {
    float a0=0.f, a1=0.f, a2=0.f, a3=0.f;
    #pragma unroll
    for (int c4 = 0; c4 < 16; ++c4){
      float4 dv = *(const float4*)&zd[c4*4];
      a0 += WT[(64 + c4*4 + 0)*64 + j]*dv.x;
      a1 += WT[(64 + c4*4 + 1)*64 + j]*dv.y;
      a2 += WT[(64 + c4*4 + 2)*64 + j]*dv.z;
      a3 += WT[(64 + c4*4 + 3)*64 + j]*dv.w;
    }
    bconst += ((a0 + a1) + (a2 + a3));
  }
  for (int t = 0; t < 64; ++t){
    if (g < 2){
      float a0=0.f, a1=0.f, a2=0.f, a3=0.f;
      #pragma unroll
      for (int c4 = 0; c4 < 16; ++c4){
        float4 pv = *(const float4*)&zp[c4*4];
        a0 += wv[c4*4+0]*pv.x; a1 += wv[c4*4+1]*pv.y;
        a2 += wv[c4*4+2]*pv.z; a3 += wv[c4*4+3]*pv.w;
      }
      float v = sigm(bconst + ((a0 + a1) + (a2 + a3)));
      if (g == 0) rz[j]   = v*zp[j];
      else        ubuf[j] = v;
    }
    __syncthreads();
    if (g == 2){
      float a0=0.f, a1=0.f, a2=0.f, a3=0.f;
      #pragma unroll
      for (int c4 = 0; c4 < 16; ++c4){
        float4 rv = *(const float4*)&rz[c4*4];
        a0 += wv[c4*4+0]*rv.x; a1 += wv[c4*4+1]*rv.y;
        a2 += wv[c4*4+2]*rv.z; a3 += wv[c4*4+3]*rv.w;
      }
      float cc = tanhf(bconst + ((a0 + a1) + (a2 + a3)));
      float u  = ubuf[j];
      float zt = (1.0f - u)*zp[j] + u*cc;
      zs[(size_t)s*4096 + t*64 + j] = zt;
      zp[j] = zt;
    }
    __syncthreads();
  }
}

// ---------------- host launch ----------------
extern "C" void kernel_launch(void* const* d_in, const int* in_sizes, int n_in,
                              void* d_out, int out_size, void* d_ws, size_t ws_size,
                              hipStream_t stream){
  static const int Vl[5] = {2048, 1024, 512, 256, 128};
  static const int El[5] = {12288, 6144, 3072, 1536, 768};
  static const int VO[4] = {0, 2048, 3072, 3584};
  static const int EO[4] = {0, 12288, 18432, 21504};

  const float* xin = (const float*)d_in[0];
  const int*   ei[4]; const float* ea[4];
  for (int l = 0; l < 4; ++l){ ei[l] = (const int*)d_in[1 + 2*l]; ea[l] = (const float*)d_in[2 + 2*l]; }
  const float* Psrc[8] = {(const float*)d_in[11], (const float*)d_in[12], (const float*)d_in[13], (const float*)d_in[14],
                          (const float*)d_in[15], (const float*)d_in[16], (const float*)d_in[17], (const float*)d_in[18]};
  const float* conv_w[4]   = {(const float*)d_in[19], (const float*)d_in[20], (const float*)d_in[21], (const float*)d_in[22]};
  const float* deconv_w[4] = {(const float*)d_in[23], (const float*)d_in[24], (const float*)d_in[25], (const float*)d_in[26]};
  const float* fce1_w = (const float*)d_in[27]; const float* fce1_b = (const float*)d_in[28];
  const float* fce2_w = (const float*)d_in[29]; const float* fce2_b = (const float*)d_in[30];
  const float* fcd3_w = (const float*)d_in[31]; const float* fcd3_b = (const float*)d_in[32];
  const float* fcd4_w = (const float*)d_in[33]; const float* fcd4_b = (const float*)d_in[34];
  const float* dom_Wih = (const float*)d_in[35]; const float* dom_Whh = (const float*)d_in[36];
  const float* dom_bih = (const float*)d_in[37]; const float* dom_bhh = (const float*)d_in[38];
  const float* dom_aggw = (const float*)d_in[39]; const float* dom_aggb = (const float*)d_in[40];
  const float* ini_Wih = (const float*)d_in[41]; const float* ini_Whh = (const float*)d_in[42];
  const float* ini_bih = (const float*)d_in[43]; const float* ini_bhh = (const float*)d_in[44];
  const float* ini_aggw = (const float*)d_in[45]; const float* ini_aggb = (const float*)d_in[46];
  const float* tr_Wr = (const float*)d_in[47]; const float* tr_br = (const float*)d_in[48];
  const float* tr_Wu = (const float*)d_in[49]; const float* tr_bu = (const float*)d_in[50];
  const float* tr_Wc = (const float*)d_in[51]; const float* tr_bc = (const float*)d_in[52];

  // ---- carve workspace ----
  char* wsp = (char*)d_ws;
  size_t off = 0;
  auto carve = [&](size_t bytes) -> void* {
    void* p = wsp + off;
    off = (off + bytes + 255) & ~(size_t)255;
    return p;
  };
  const size_t BUFCAP = (size_t)NB*2048*8*64;
  float* bufA = (float*)carve(BUFCAP*4);   // holds GI_dom (bf16) during latent phase
  float* bufB = (float*)carve(BUFCAP*4);   // holds GI_ini (bf16) during latent phase
  void* webt = carve((size_t)NB*1024*1024*2 + 1024);
  float*  We = (float*)webt;
  ushort* BT = (ushort*)webt;
  ushort* xT = (ushort*)webt;
  ushort* WeTb = (ushort*)carve((size_t)1536*64*32*2 + 1024);
  ushort* embB2 = (ushort*)carve((size_t)1024*64*64*2);
  float* zD   = (float*)carve((size_t)NB*128*64*4);
  float* z0   = (float*)carve((size_t)NB*128*64*4);
  float* domWhhT = (float*)carve(12288*4);
  float* iniWhhT = (float*)carve(12288*4);
  float* domAggT = (float*)carve(4096*4);
  float* iniAggT = (float*)carve(4096*4);
  float* trWrT   = (float*)carve(8192*4);
  float* trWuT   = (float*)carve(8192*4);
  float* trWcT   = (float*)carve(8192*4);
  ushort* WihPadD = (ushort*)carve(256*64*2);
  ushort* WihPadI = (ushort*)carve(256*64*2);
  ushort* Wfce1b = (ushort*)carve(8192*2);
  ushort* Wfce2b = (ushort*)carve(8192*2);
  ushort* Wfcd3b = (ushort*)carve(8192*2);
  ushort* Wfcd4b = (ushort*)carve(8192*2);
  static const int PM[8] = {1024, 512, 256, 128, 256, 512, 1024, 2048};
  static const int PK[8] = {2048, 1024, 512, 256, 128, 256, 512, 1024};
  ushort* Pb[8];
  for (int i = 0; i < 8; ++i) Pb[i] = (ushort*)carve((size_t)PM[i]*PK[i]*2);
  int* deg_all    = (int*)carve(TOTV*4);
  int* cursor_all = (int*)carve(TOTV*4);
  int* rowptr_all = (int*)carve((TOTV + 4)*4);
  int* elist_all  = (int*)carve(TOTE*4);
  (void)ws_size; (void)in_sizes; (void)n_in; (void)out_size;

  // ---- weight transposes + bf16 conversions ----
  auto tr = [&](const float* in, float* out, int R, int C){
    transpose_kernel<<<(R*C + 255)/256, 256, 0, stream>>>(in, out, R, C);
  };
  tr(dom_Whh, domWhhT, 192, 64);  tr(ini_Whh, iniWhhT, 192, 64);
  tr(dom_aggw, domAggT, 64, 64);  tr(ini_aggw, iniAggT, 64, 64);
  tr(tr_Wr, trWrT, 64, 128);  tr(tr_Wu, trWuT, 64, 128);  tr(tr_Wc, trWcT, 64, 128);
  pad_wih<<<64, 256, 0, stream>>>(dom_Wih, WihPadD);
  pad_wih<<<64, 256, 0, stream>>>(ini_Wih, WihPadI);
  conv_bf16<<<32, 256, 0, stream>>>(fce1_w, Wfce1b, 8192);
  conv_bf16<<<32, 256, 0, stream>>>(fce2_w, Wfce2b, 8192);
  conv_bf16<<<32, 256, 0, stream>>>(fcd3_w, Wfcd3b, 8192);
  conv_bf16<<<32, 256, 0, stream>>>(fcd4_w, Wfcd4b, 8192);
  for (int i = 0; i < 8; ++i){
    int nel = PM[i]*PK[i];
    conv_bf16<<<(nel + 255)/256, 256, 0, stream>>>(Psrc[i], Pb[i], nel);
  }

  // ---- parallel CSR build ----
  const int* dsts[4] = {ei[0] + El[0], ei[1] + El[1], ei[2] + El[2], ei[3] + El[3]};
  csr_zero<<<(TOTV + 255)/256, 256, 0, stream>>>(deg_all);
  csr_deg <<<(TOTE + 255)/256, 256, 0, stream>>>(dsts[0], dsts[1], dsts[2], dsts[3], deg_all);
  csr_scan<<<4, 1024, 0, stream>>>(deg_all, rowptr_all, cursor_all);
  csr_fill<<<(TOTE + 255)/256, 256, 0, stream>>>(dsts[0], dsts[1], dsts[2], dsts[3], cursor_all, elist_all);
  csr_sort<<<(TOTV + 255)/256, 256, 0, stream>>>(rowptr_all, elist_all);

  // ---- stage helpers ----
  auto gconv = [&](const float* in, float* out, int l, const float* Wb, int Ci, int Co){
    int CiCo = Ci*Co;
    int tot = El[l]*CiCo;
    edge_we_kernel<<<(tot + 255)/256, 256, 0, stream>>>(ea[l], Wb, We, El[l], CiCo);
    int nblk = NB*Vl[l];
    const int* rp = rowptr_all + VO[l] + l;
    const int* el = elist_all + EO[l];
    #define GCASE(CI,CO) if (Ci==CI && Co==CO) gconv2_kernel<CI,CO><<<nblk, 256, 0, stream>>>(in, We, ei[l], rp, el, out, Vl[l]);
    GCASE(1,8)  GCASE(8,16)  GCASE(16,8)  GCASE(8,1)
    #undef GCASE
  };
  auto gconv_m = [&](const float* in, float* out, int l, const float* Wb, int Ci, int Co){
    int S = NB*Vl[l];
    int CiP = (Ci < 32) ? 32 : Ci;
    if (Ci == 16)      xpose_bf16<16,32><<<S, 256, 0, stream>>>(in, xT);
    else if (Ci == 32) xpose_bf16<32,32><<<S, 256, 0, stream>>>(in, xT);
    else               xpose_bf16<64,64><<<S, 256, 0, stream>>>(in, xT);
    if (Ci == 16 && Co == 32)      edge_weT2<16,32,32><<<El[l], 256, 0, stream>>>(ea[l], Wb, WeTb);
    else if (Ci == 32 && Co == 64) edge_weT2<32,64,32><<<El[l], 256, 0, stream>>>(ea[l], Wb, WeTb);
    else if (Ci == 64 && Co == 32) edge_weT2<64,32,64><<<El[l], 256, 0, stream>>>(ea[l], Wb, WeTb);
    else if (Ci == 32 && Co == 16) edge_weT2<32,16,32><<<El[l], 256, 0, stream>>>(ea[l], Wb, WeTb);
    const int* rp = rowptr_all + VO[l] + l;
    const int* el = elist_all + EO[l];
    #define GMC(CIP,CO) if (CiP==CIP && Co==CO) gconv_mfma4<CIP,CO><<<S, 256, 0, stream>>>(xT, WeTb, ei[l], rp, el, out, Vl[l]);
    GMC(32,32) GMC(32,64) GMC(64,32) GMC(32,16)
    #undef GMC
  };
  auto pool2 = [&](int pi, const float* hin, float* out, int M, int K, int NN){
    dim3 tg(NN/64, K/64, NB);
    transp_bf16<<<tg, 256, 0, stream>>>(hin, BT, K, NN);
    dim3 g(NN/64, M/64, NB);
    pool_mfma64<0><<<g, 256, 0, stream>>>(Pb[pi], BT, (void*)out, M, K, NN);
  };

  // ---- encoder ----
  gconv(xin,  bufA, 0, conv_w[0], 1, 8);
  pool2(0, bufA, bufB, 1024, 2048, 512);
  gconv(bufB, bufA, 1, conv_w[1], 8, 16);
  pool2(1, bufA, bufB, 512, 1024, 1024);
  gconv_m(bufB, bufA, 2, conv_w[2], 16, 32);
  pool2(2, bufA, bufB, 256, 512, 2048);
  gconv_m(bufB, bufA, 3, conv_w[3], 32, 64);
  pool2(3, bufA, bufB, 128, 256, 4096);

  // fused fce1+fce2: (s,64,t) fp32 -> emb (s,t,64) bf16 (ELU then tanh)
  pw2_mfma<64,128,64,1,2,0,1><<<1024, 256, 0, stream>>>(bufB, Wfce1b, fce1_b, Wfce2b, fce2_b, embB2);

  // ---- latent ----
  dim3 gg(4, 1024, 1);
  pool_mfma64<1><<<gg, 256, 0, stream>>>(embB2, WihPadD, (void*)bufA, 65536, 64, 256);
  pool_mfma64<1><<<gg, 256, 0, stream>>>(embB2, WihPadI, (void*)bufB, 65536, 64, 256);
  gru3m_kernel<<<2*NB*128, 192, 0, stream>>>((const ushort*)bufA, (const ushort*)bufB,
      domWhhT, iniWhhT, dom_bih, dom_bhh, domAggT, dom_aggb,
      ini_bih, ini_bhh, iniAggT, ini_aggb, zD, z0, NB*128);
  trans2_kernel<<<NB*128, 192, 0, stream>>>(z0, zD, trWrT, trWuT, trWcT, tr_br, tr_bu, tr_bc, bufA);

  // ---- decoder ----
  pw2_mfma<64,128,64,1,1,1,0><<<1024, 256, 0, stream>>>(bufA, Wfcd3b, fcd3_b, Wfcd4b, fcd4_b, bufB);
  pool2(4, bufB, bufA, 256, 128, 4096);
  gconv_m(bufA, bufB, 3, deconv_w[0], 64, 32);
  pool2(5, bufB, bufA, 512, 256, 2048);
  gconv_m(bufA, bufB, 2, deconv_w[1], 32, 16);
  pool2(6, bufB, bufA, 1024, 512, 1024);
  gconv(bufA, bufB, 1, deconv_w[2], 16, 8);
  pool2(7, bufB, bufA, 2048, 1024, 512);
  gconv(bufA, (float*)d_out, 0, deconv_w[3], 8, 1);
}

// Round 16
// 791.443 us; speedup vs baseline: 1.0263x; 1.0263x over previous
//
#include <hip/hip_runtime.h>

#define NB 8   // batch
#define TT 64  // time

typedef __attribute__((ext_vector_type(8))) short bf16x8_t;
typedef __attribute__((ext_vector_type(4))) float f32x4_t;

__device__ __forceinline__ float sigm(float x){ return 1.0f/(1.0f+expf(-x)); }
__device__ __forceinline__ float eluf(float x){ return x>0.0f ? x : expm1f(x); }
__device__ __forceinline__ ushort f2bf(float f){
  uint u = __float_as_uint(f);
  return (ushort)((u + 0x7FFFu + ((u >> 16) & 1u)) >> 16);   // RNE
}
__device__ __forceinline__ float bf2f(ushort u){
  return __uint_as_float(((uint)u) << 16);
}

// CSR fused-level geometry (levels 0..3)
__device__ __constant__ int c_VL[4] = {2048, 1024, 512, 256};
__device__ __constant__ int c_VO[4] = {0, 2048, 3072, 3584};
__device__ __constant__ int c_EO[4] = {0, 12288, 18432, 21504};
#define TOTV 3840
#define TOTE 23040

// ---------------- fused weight prep (replaces 21 tiny kernels) ----------------
#define NPREP 21
struct PrepTasks {
  const float* src[NPREP];
  void* dst[NPREP];
  int R[NPREP], C[NPREP];
  int type[NPREP];   // 0: fp32 transpose; 1: pad_wih (192->256 rows, bf16); 2: bf16 convert
  int blk0[NPREP + 1];
  int ntask;
};

__global__ __launch_bounds__(256) void prep_all(PrepTasks T){
  int b = blockIdx.x;
  int t = 0;
  while (t + 1 < T.ntask && b >= T.blk0[t+1]) ++t;
  int idx = (b - T.blk0[t])*256 + threadIdx.x;
  int n = T.R[t]*T.C[t];
  if (idx >= n) return;
  int ty = T.type[t];
  if (ty == 0){
    int C = T.C[t];
    int r = idx / C, c = idx - r*C;
    ((float*)T.dst[t])[c*T.R[t] + r] = T.src[t][idx];
  } else if (ty == 1){
    int r = idx >> 6;
    ((ushort*)T.dst[t])[idx] = (r < 192) ? f2bf(T.src[t][idx]) : (ushort)0;
  } else {
    ((ushort*)T.dst[t])[idx] = f2bf(T.src[t][idx]);
  }
}

// transpose+convert: in (NB, R, C) fp32 -> out (NB, C, R) bf16  (for pool BT)
__global__ __launch_bounds__(256) void transp_bf16(
    const float* __restrict__ in, ushort* __restrict__ out, int R, int Ccols){
  __shared__ float tile[64][65];
  int n = blockIdx.z;
  const float* ip = in + (size_t)n*R*Ccols;
  ushort* op = out + (size_t)n*R*Ccols;
  int tid = threadIdx.x;
  int tx = tid & 63, ty = tid >> 6;
  int r0 = blockIdx.y*64, c0 = blockIdx.x*64;
  #pragma unroll
  for (int i = 0; i < 64; i += 4)
    tile[ty+i][tx] = ip[(size_t)(r0+ty+i)*Ccols + c0 + tx];
  __syncthreads();
  #pragma unroll
  for (int i = 0; i < 64; i += 4)
    op[(size_t)(c0+ty+i)*R + r0 + tx] = f2bf(tile[tx][ty+i]);
}

// per-vertex activation transpose: in (S, Ci, 64) fp32 -> out (S, 64, CiP) bf16, zero-pad ci>=Ci
template<int Ci, int CiP>
__global__ __launch_bounds__(256) void xpose_bf16(const float* __restrict__ in, ushort* __restrict__ out){
  __shared__ float tile[Ci][65];
  int s = blockIdx.x, tid = threadIdx.x;
  const float* ip = in + (size_t)s*Ci*64;
  for (int i = tid; i < Ci*64; i += 256) tile[i>>6][i&63] = ip[i];
  __syncthreads();
  ushort* op = out + (size_t)s*64*CiP;
  for (int i = tid; i < 64*CiP; i += 256){
    int t = i / CiP, ci = i - t*CiP;
    op[i] = (ci < Ci) ? f2bf(tile[ci][t]) : (ushort)0;
  }
}

// ---------------- parallel CSR build ----------------
__global__ void csr_zero(int* __restrict__ deg_all){
  int i = blockIdx.x*256 + threadIdx.x;
  if (i < TOTV) deg_all[i] = 0;
}

__global__ void csr_deg(const int* __restrict__ d0, const int* __restrict__ d1,
                        const int* __restrict__ d2, const int* __restrict__ d3,
                        int* __restrict__ deg_all){
  int idx = blockIdx.x*256 + threadIdx.x;
  if (idx >= TOTE) return;
  int l = (idx < 12288) ? 0 : (idx < 18432) ? 1 : (idx < 21504) ? 2 : 3;
  int e = idx - c_EO[l];
  const int* dl = (l==0)?d0:(l==1)?d1:(l==2)?d2:d3;
  atomicAdd(&deg_all[c_VO[l] + dl[e]], 1);
}

__global__ __launch_bounds__(1024) void csr_scan(const int* __restrict__ deg_all,
                                                 int* __restrict__ rowptr_all,
                                                 int* __restrict__ cursor_all){
  __shared__ int a[2048], b[2048];
  int l = blockIdx.x;
  int Vv = c_VL[l], vo = c_VO[l], eo = c_EO[l];
  int tid = threadIdx.x;
  for (int i = tid; i < 2048; i += 1024) a[i] = (i < Vv) ? deg_all[vo + i] : 0;
  __syncthreads();
  int* s = a; int* d = b;
  for (int off = 1; off < 2048; off <<= 1){
    for (int i = tid; i < 2048; i += 1024) d[i] = s[i] + ((i >= off) ? s[i-off] : 0);
    __syncthreads();
    int* t = s; s = d; d = t;
  }
  int rbase = vo + l;
  for (int i = tid; i < Vv; i += 1024){
    int excl = (i == 0) ? 0 : s[i-1];
    rowptr_all[rbase + i] = excl;
    cursor_all[vo + i]    = eo + excl;
  }
  if (tid == 0) rowptr_all[rbase + Vv] = s[2047];
}

__global__ void csr_fill(const int* __restrict__ d0, const int* __restrict__ d1,
                         const int* __restrict__ d2, const int* __restrict__ d3,
                         int* __restrict__ cursor_all, int* __restrict__ elist_all){
  int idx = blockIdx.x*256 + threadIdx.x;
  if (idx >= TOTE) return;
  int l = (idx < 12288) ? 0 : (idx < 18432) ? 1 : (idx < 21504) ? 2 : 3;
  int e = idx - c_EO[l];
  const int* dl = (l==0)?d0:(l==1)?d1:(l==2)?d2:d3;
  int p = atomicAdd(&cursor_all[c_VO[l] + dl[e]], 1);
  elist_all[p] = e;
}

__global__ void csr_sort(const int* __restrict__ rowptr_all, int* __restrict__ elist_all){
  int idx = blockIdx.x*256 + threadIdx.x;
  if (idx >= TOTV) return;
  int l = (idx < 2048) ? 0 : (idx < 3072) ? 1 : (idx < 3584) ? 2 : 3;
  int v = idx - c_VO[l];
  int rbase = c_VO[l] + l, eo = c_EO[l];
  int s = eo + rowptr_all[rbase + v], epos = eo + rowptr_all[rbase + v + 1];
  for (int i = s + 1; i < epos; ++i){
    int key = elist_all[i];
    int j = i - 1;
    while (j >= s && elist_all[j] > key){ elist_all[j+1] = elist_all[j]; --j; }
    elist_all[j+1] = key;
  }
}

// B-spline edge weights (fp32, for vector gconv levels 0/1)
__global__ void edge_we_kernel(const float* __restrict__ attr, const float* __restrict__ Wb,
                               float* __restrict__ We, int E, int CiCo){
  int idx = blockIdx.x*256 + threadIdx.x;
  if (idx >= E*CiCo) return;
  int e = idx / CiCo, r = idx - e*CiCo;
  float f[3]; int i0[3];
  #pragma unroll
  for (int d = 0; d < 3; ++d){
    float p  = attr[e*3+d]*2.0f;
    float fl = fminf(fmaxf(floorf(p), 0.0f), 1.0f);
    i0[d] = (int)fl;
    f[d]  = p - fl;
  }
  float acc = 0.0f;
  #pragma unroll
  for (int c0 = 0; c0 < 2; ++c0){
    float w0 = c0 ? f[0] : 1.0f - f[0];
    #pragma unroll
    for (int c1 = 0; c1 < 2; ++c1){
      float w1 = c1 ? f[1] : 1.0f - f[1];
      #pragma unroll
      for (int c2 = 0; c2 < 2; ++c2){
        float w2 = c2 ? f[2] : 1.0f - f[2];
        int flat = (i0[0]+c0)*9 + (i0[1]+c1)*3 + (i0[2]+c2);
        acc += w0*w1*w2 * Wb[flat*CiCo + r];
      }
    }
  }
  We[idx] = acc;
}

// B-spline -> transposed bf16 WeT[e, co, ciP]: block-per-edge, coalesced reads, LDS transpose
template<int Ci, int Co, int CiP>
__global__ __launch_bounds__(256) void edge_weT2(
    const float* __restrict__ attr, const float* __restrict__ Wb,
    ushort* __restrict__ WeT){
  __shared__ float s[Ci][Co + 1];
  int e = blockIdx.x, tid = threadIdx.x;
  float f[3]; int i0[3];
  #pragma unroll
  for (int d = 0; d < 3; ++d){
    float p  = attr[e*3+d]*2.0f;
    float fl = fminf(fmaxf(floorf(p), 0.0f), 1.0f);
    i0[d] = (int)fl;
    f[d]  = p - fl;
  }
  float w[8]; int fl8[8];
  #pragma unroll
  for (int c0 = 0; c0 < 2; ++c0)
    #pragma unroll
    for (int c1 = 0; c1 < 2; ++c1)
      #pragma unroll
      for (int c2 = 0; c2 < 2; ++c2){
        int k = c0*4 + c1*2 + c2;
        w[k] = (c0 ? f[0] : 1.0f - f[0]) * (c1 ? f[1] : 1.0f - f[1]) * (c2 ? f[2] : 1.0f - f[2]);
        fl8[k] = (i0[0]+c0)*9 + (i0[1]+c1)*3 + (i0[2]+c2);
      }
  constexpr int CiCo = Ci*Co;
  for (int r = tid; r < CiCo; r += 256){
    float acc = 0.0f;
    #pragma unroll
    for (int k = 0; k < 8; ++k) acc += w[k]*Wb[fl8[k]*CiCo + r];
    s[r/Co][r - (r/Co)*Co] = acc;
  }
  __syncthreads();
  ushort* op = WeT + (size_t)e*(Co*CiP);
  for (int r2 = tid; r2 < Co*CiP; r2 += 256){
    int co = r2 / CiP, ci = r2 - co*CiP;
    op[r2] = (ci < Ci) ? f2bf(s[ci][co]) : (ushort)0;
  }
}

// ---------------- graph conv (vector path, levels 0/1) ----------------
template<int Ci, int Co>
__global__ __launch_bounds__(256) void gconv2_kernel(
    const float* __restrict__ x, const float* __restrict__ We,
    const int* __restrict__ src_arr, const int* __restrict__ rowptr,
    const int* __restrict__ elist, float* __restrict__ out, int V){
  constexpr int CiCo = Ci*Co;
  __shared__ float ws[4][CiCo];
  __shared__ float red[Co*64];
  int blk = blockIdx.x;
  int n = blk / V, v = blk - n*V;
  int tid = threadIdx.x;
  int w = tid >> 6, lane = tid & 63;
  int rs = rowptr[v], re = rowptr[v+1];
  float acc[Co];
  #pragma unroll
  for (int i = 0; i < Co; ++i) acc[i] = 0.0f;

  for (int q = rs + w; q < re; q += 4){
    int e   = elist[q];
    int src = src_arr[e];
    const float* wsrc = We + (size_t)e*CiCo;
    #pragma unroll
    for (int i = lane; i < CiCo; i += 64) ws[w][i] = wsrc[i];
    __builtin_amdgcn_s_waitcnt(0);
    const float* xp = x + ((size_t)(n*V + src))*(Ci*64) + lane;
    #pragma unroll 4
    for (int ci = 0; ci < Ci; ++ci){
      float xv = xp[(size_t)ci*64];
      if constexpr (Co >= 4){
        #pragma unroll
        for (int co = 0; co < Co; co += 4){
          float4 wv = *(const float4*)&ws[w][ci*Co + co];
          acc[co+0] += wv.x*xv;
          acc[co+1] += wv.y*xv;
          acc[co+2] += wv.z*xv;
          acc[co+3] += wv.w*xv;
        }
      } else {
        #pragma unroll
        for (int co = 0; co < Co; ++co) acc[co] += ws[w][ci*Co + co]*xv;
      }
    }
  }

  if (w == 0){
    #pragma unroll
    for (int co = 0; co < Co; ++co) red[co*64 + lane] = acc[co];
  }
  __syncthreads();
  #pragma unroll
  for (int ww = 1; ww < 4; ++ww){
    if (w == ww){
      #pragma unroll
      for (int co = 0; co < Co; ++co) red[co*64 + lane] += acc[co];
    }
    __syncthreads();
  }
  float scale = 1.0f / fmaxf((float)(re - rs), 1.0f);
  size_t ob = ((size_t)(n*V + v))*(Co*64);
  for (int co = w; co < Co; co += 4)
    out[ob + (size_t)co*64 + lane] = eluf(red[co*64 + lane]*scale);
}

// ---------------- graph conv (MFMA path, levels 2/3), wave-split edges, XCD-coherent ----------------
template<int CiP, int Co>
__global__ __launch_bounds__(256, 4) void gconv_mfma4(
    const ushort* __restrict__ xT, const ushort* __restrict__ WeT,
    const int* __restrict__ src_arr, const int* __restrict__ rowptr,
    const int* __restrict__ elist, float* __restrict__ out, int V){
  constexpr int MT = Co/16, KT = CiP/32;
  __shared__ int2 es[64];
  __shared__ float red[Co*64];
  int bid = blockIdx.x;
  int r8 = bid & 7, q0 = bid >> 3;
  int n = q0 & 7;                 // NB = 8
  int v = ((q0 >> 3) << 3) | r8;  // V multiple of 8
  int tid = threadIdx.x;
  int w = tid >> 6, lane = tid & 63;
  int l15 = lane & 15, g = lane >> 4;
  int rs = rowptr[v], re = rowptr[v+1];
  int deg = re - rs;
  int cnt0 = (deg < 64) ? deg : 64;
  if (tid < cnt0){
    int e = elist[rs + tid];
    es[tid] = make_int2(e, src_arr[e]);
  }
  __syncthreads();
  f32x4_t acc[MT][4];
  #pragma unroll
  for (int m = 0; m < MT; ++m)
    #pragma unroll
    for (int tt = 0; tt < 4; ++tt) acc[m][tt] = (f32x4_t){0.f,0.f,0.f,0.f};
  for (int q = w; q < deg; q += 4){
    int e, src;
    if (q < 64){ e = es[q].x; src = es[q].y; }
    else { e = elist[rs + q]; src = src_arr[e]; }
    const ushort* xp = xT + ((size_t)(n*V + src))*(64*CiP) + (size_t)l15*CiP + g*8;
    const ushort* wp = WeT + (size_t)e*(Co*CiP) + (size_t)l15*CiP + g*8;
    #pragma unroll
    for (int kt = 0; kt < KT; ++kt){
      bf16x8_t bfrag[4];
      #pragma unroll
      for (int tt = 0; tt < 4; ++tt)
        bfrag[tt] = *(const bf16x8_t*)(xp + (size_t)tt*16*CiP + kt*32);
      #pragma unroll
      for (int m = 0; m < MT; ++m){
        bf16x8_t afrag = *(const bf16x8_t*)(wp + (size_t)m*16*CiP + kt*32);
        #pragma unroll
        for (int tt = 0; tt < 4; ++tt)
          acc[m][tt] = __builtin_amdgcn_mfma_f32_16x16x32_bf16(afrag, bfrag[tt], acc[m][tt], 0, 0, 0);
      }
    }
  }
  if (w == 0){
    #pragma unroll
    for (int m = 0; m < MT; ++m)
      #pragma unroll
      for (int tt = 0; tt < 4; ++tt)
        #pragma unroll
        for (int r = 0; r < 4; ++r)
          red[(m*16 + g*4 + r)*64 + tt*16 + l15] = acc[m][tt][r];
  }
  __syncthreads();
  #pragma unroll
  for (int ww = 1; ww < 4; ++ww){
    if (w == ww){
      #pragma unroll
      for (int m = 0; m < MT; ++m)
        #pragma unroll
        for (int tt = 0; tt < 4; ++tt)
          #pragma unroll
          for (int r = 0; r < 4; ++r)
            red[(m*16 + g*4 + r)*64 + tt*16 + l15] += acc[m][tt][r];
    }
    __syncthreads();
  }
  float scale = 1.0f / fmaxf((float)deg, 1.0f);
  size_t ob = ((size_t)(n*V + v))*(Co*64);
  for (int i = tid; i < Co*64; i += 256)
    out[ob + i] = eluf(red[i]*scale);
}

// ---------------- 64x64-tile MFMA GEMM: C[z] = A @ BT[z]^T ----------------
template<int OUTBF>
__global__ __launch_bounds__(256) void pool_mfma64(
    const ushort* __restrict__ A, const ushort* __restrict__ BT, void* __restrict__ Cout,
    int M, int K, int NN){
  __shared__ ushort As[64*40];
  __shared__ ushort Bs[64*40];
  char* Asb = (char*)As; char* Bsb = (char*)Bs;
  int tid = threadIdx.x;
  int wv = tid >> 6, lane = tid & 63;
  int g = lane >> 4, l15 = lane & 15;
  int wr = wv >> 1, wc = wv & 1;
  int m0 = blockIdx.y*64, n0 = blockIdx.x*64;
  const ushort* Bp = BT + (size_t)blockIdx.z*((size_t)NN*K);
  f32x4_t acc[2][2];
  #pragma unroll
  for (int i = 0; i < 2; ++i)
    #pragma unroll
    for (int j = 0; j < 2; ++j) acc[i][j] = (f32x4_t){0.f,0.f,0.f,0.f};
  int srow = tid >> 2, slot = tid & 3;
  int wbo = srow*80 + slot*16;
  const ushort* gA = A  + (size_t)(m0+srow)*K + slot*8;
  const ushort* gB = Bp + (size_t)(n0+srow)*K + slot*8;
  for (int k0 = 0; k0 < K; k0 += 32){
    uint4 va = *(const uint4*)(gA + k0);
    uint4 vb = *(const uint4*)(gB + k0);
    __syncthreads();
    *(uint4*)(Asb + wbo) = va;
    *(uint4*)(Bsb + wbo) = vb;
    __syncthreads();
    bf16x8_t af[2], bfr[2];
    #pragma unroll
    for (int f = 0; f < 2; ++f){
      af[f]  = *(const bf16x8_t*)(Asb + (wr*32 + f*16 + l15)*80 + g*16);
      bfr[f] = *(const bf16x8_t*)(Bsb + (wc*32 + f*16 + l15)*80 + g*16);
    }
    #pragma unroll
    for (int fm = 0; fm < 2; ++fm)
      #pragma unroll
      for (int fn = 0; fn < 2; ++fn)
        acc[fm][fn] = __builtin_amdgcn_mfma_f32_16x16x32_bf16(af[fm], bfr[fn], acc[fm][fn], 0, 0, 0);
  }
  #pragma unroll
  for (int fm = 0; fm < 2; ++fm){
    int row = m0 + wr*32 + fm*16 + g*4;
    #pragma unroll
    for (int fn = 0; fn < 2; ++fn){
      int col = n0 + wc*32 + fn*16 + l15;
      if constexpr (OUTBF){
        ushort* Cb = (ushort*)Cout + (size_t)blockIdx.z*((size_t)M*NN);
        #pragma unroll
        for (int r = 0; r < 4; ++r)
          Cb[(size_t)(row + r)*NN + col] = f2bf(acc[fm][fn][r]);
      } else {
        float* Cf = (float*)Cout + (size_t)blockIdx.z*((size_t)M*NN);
        #pragma unroll
        for (int r = 0; r < 4; ++r)
          Cf[(size_t)(row + r)*NN + col] = acc[fm][fn][r];
      }
    }
  }
}

// ---------------- fused dual MFMA pointwise: out = act2(W2 @ act1(W1 @ x + b1) + b2) ----------------
template<int C, int O1, int O2, int ACT1, int ACT2, int INF, int OUTF>
__global__ __launch_bounds__(256) void pw2_mfma(
    const void* __restrict__ inv,
    const ushort* __restrict__ W1, const float* __restrict__ b1,
    const ushort* __restrict__ W2, const float* __restrict__ b2,
    void* __restrict__ outv){
  constexpr int CP = C + 8, O1P = O1 + 8;
  constexpr int MT1 = O1/16, KT1 = C/32;
  constexpr int MT2 = O2/16, KT2 = O1/32;
  __shared__ ushort XT[64*CP];
  __shared__ ushort YT[64*O1P];
  int s = blockIdx.x, tid = threadIdx.x;
  int w = tid >> 6, lane = tid & 63;
  int l15 = lane & 15, g = lane >> 4;
  if constexpr (INF == 0){
    const float* ip = (const float*)inv + (size_t)s*C*64;
    for (int i = tid; i < C*64; i += 256){ int c = i >> 6, t = i & 63; XT[t*CP + c] = f2bf(ip[i]); }
  } else {
    const float* ip = (const float*)inv + (size_t)s*64*C;
    for (int i = tid; i < C*64; i += 256){ int t = i / C, c = i - t*C; XT[t*CP + c] = f2bf(ip[i]); }
  }
  __syncthreads();
  int trow = w*16 + l15;
  {
    f32x4_t acc[MT1];
    #pragma unroll
    for (int m = 0; m < MT1; ++m) acc[m] = (f32x4_t){0.f,0.f,0.f,0.f};
    #pragma unroll
    for (int kt = 0; kt < KT1; ++kt){
      bf16x8_t bfrag = *(const bf16x8_t*)(&XT[trow*CP + kt*32 + g*8]);
      #pragma unroll
      for (int m = 0; m < MT1; ++m){
        bf16x8_t afrag = *(const bf16x8_t*)(W1 + (size_t)(m*16 + l15)*C + kt*32 + g*8);
        acc[m] = __builtin_amdgcn_mfma_f32_16x16x32_bf16(afrag, bfrag, acc[m], 0, 0, 0);
      }
    }
    #pragma unroll
    for (int m = 0; m < MT1; ++m){
      #pragma unroll
      for (int r = 0; r < 4; ++r){
        int o = m*16 + g*4 + r;
        float v = acc[m][r] + b1[o];
        v = (ACT1 == 1) ? eluf(v) : tanhf(v);
        YT[trow*O1P + o] = f2bf(v);
      }
    }
  }
  __syncthreads();
  {
    f32x4_t acc[MT2];
    #pragma unroll
    for (int m = 0; m < MT2; ++m) acc[m] = (f32x4_t){0.f,0.f,0.f,0.f};
    #pragma unroll
    for (int kt = 0; kt < KT2; ++kt){
      bf16x8_t bfrag = *(const bf16x8_t*)(&YT[trow*O1P + kt*32 + g*8]);
      #pragma unroll
      for (int m = 0; m < MT2; ++m){
        bf16x8_t afrag = *(const bf16x8_t*)(W2 + (size_t)(m*16 + l15)*O1 + kt*32 + g*8);
        acc[m] = __builtin_amdgcn_mfma_f32_16x16x32_bf16(afrag, bfrag, acc[m], 0, 0, 0);
      }
    }
    if constexpr (OUTF == 0){
      float* op = (float*)outv + (size_t)s*O2*64;
      #pragma unroll
      for (int m = 0; m < MT2; ++m){
        #pragma unroll
        for (int r = 0; r < 4; ++r){
          int o = m*16 + g*4 + r;
          float v = acc[m][r] + b2[o];
          v = (ACT2 == 1) ? eluf(v) : tanhf(v);
          op[(size_t)o*64 + trow] = v;
        }
      }
    } else {
      constexpr int O2P = O2 + 8;
      #pragma unroll
      for (int m = 0; m < MT2; ++m){
        #pragma unroll
        for (int r = 0; r < 4; ++r){
          int o = m*16 + g*4 + r;
          float v = acc[m][r] + b2[o];
          v = (ACT2 == 1) ? eluf(v) : tanhf(v);
          XT[trow*O2P + o] = f2bf(v);
        }
      }
      __syncthreads();
      ushort* op = (ushort*)outv + (size_t)s*64*O2;
      for (int i = tid; i < 64*O2; i += 256){
        int t = i / O2, o = i - t*O2;
        op[i] = XT[t*O2P + o];
      }
    }
  }
}

// ---------------- merged GRU scans (dom + ini), gate-per-wave; GI stride 512 ----------------
// GI: (S*64, 512) bf16: cols 0-255 dom gates, 256-511 ini gates
__global__ __launch_bounds__(192) void gru3m_kernel(
    const ushort* __restrict__ GI,
    const float* __restrict__ WhhT_d, const float* __restrict__ WhhT_i,
    const float* __restrict__ bih_d, const float* __restrict__ bhh_d,
    const float* __restrict__ aggT_d, const float* __restrict__ aggb_d,
    const float* __restrict__ bih_i, const float* __restrict__ bhh_i,
    const float* __restrict__ aggT_i, const float* __restrict__ aggb_i,
    float* __restrict__ zD, float* __restrict__ z0, int S){
  __shared__ float hsh[64];
  __shared__ float rbuf[64];
  __shared__ float zbuf[64];
  int bid = blockIdx.x;
  bool dom = (bid < S);
  int s = dom ? bid : bid - S;
  int TS = dom ? 64 : 16;
  const float* WhhT  = dom ? WhhT_d : WhhT_i;
  const float* bih   = dom ? bih_d  : bih_i;
  const float* bhh   = dom ? bhh_d  : bhh_i;
  const float* aggT  = dom ? aggT_d : aggT_i;
  const float* aggb  = dom ? aggb_d : aggb_i;
  float* zout        = dom ? zD     : z0;
  int tid = threadIdx.x;
  int g = tid >> 6, j = tid & 63;
  if (tid < 64) hsh[tid] = 0.0f;
  float whh[64];
  #pragma unroll
  for (int c = 0; c < 64; ++c) whh[c] = WhhT[c*192 + tid];
  float b_i = bih[tid], b_h = bhh[tid];
  const ushort* gp = GI + (size_t)s*64*512 + (dom ? 0 : 256) + tid;
  float gi_cur = b_i + bf2f(gp[0]);
  __syncthreads();
  for (int t = 0; t < TS; ++t){
    ushort gnx = (t + 1 < TS) ? gp[(size_t)(t+1)*512] : (ushort)0;
    float gh0 = 0.f, gh1 = 0.f;
    #pragma unroll
    for (int c4 = 0; c4 < 16; ++c4){
      float4 hv = *(const float4*)&hsh[c4*4];
      gh0 += whh[c4*4+0]*hv.x; gh1 += whh[c4*4+1]*hv.y;
      gh0 += whh[c4*4+2]*hv.z; gh1 += whh[c4*4+3]*hv.w;
    }
    float gh = b_h + gh0 + gh1;
    if (g == 0)      rbuf[j] = sigm(gi_cur + gh);
    else if (g == 1) zbuf[j] = sigm(gi_cur + gh);
    __syncthreads();
    if (g == 2){
      float gg = tanhf(gi_cur + rbuf[j]*gh);
      float z  = zbuf[j];
      hsh[j] = (1.0f - z)*gg + z*hsh[j];
    }
    __syncthreads();
    gi_cur = b_i + bf2f(gnx);
  }
  if (tid < 64){
    float a = aggb[tid];
    #pragma unroll
    for (int c = 0; c < 64; ++c) a += aggT[c*64 + tid]*hsh[c];
    zout[(size_t)s*64 + tid] = tanhf(a);
  }
}

// ---------------- transition: gate-per-wave, register weights (r14 2-acc version) ----------------
__global__ __launch_bounds__(192) void trans2_kernel(
    const float* __restrict__ z0, const float* __restrict__ zD,
    const float* __restrict__ WrT, const float* __restrict__ WuT, const float* __restrict__ WcT,
    const float* __restrict__ br, const float* __restrict__ bu, const float* __restrict__ bc,
    float* __restrict__ zs){
  __shared__ float zp[64];
  __shared__ float zd[64];
  __shared__ float rz[64];
  __shared__ float ubuf[64];
  int s = blockIdx.x, tid = threadIdx.x;
  int g = tid >> 6, j = tid & 63;
  if (tid < 64){ zp[tid] = z0[(size_t)s*64 + tid]; zd[tid] = zD[(size_t)s*64 + tid]; }
  const float* WT = (g == 0) ? WrT : (g == 1) ? WuT : WcT;
  const float* bb = (g == 0) ? br  : (g == 1) ? bu  : bc;
  float wv[64];
  #pragma unroll
  for (int c = 0; c < 64; ++c) wv[c] = WT[c*64 + j];
  float bconst = bb[j];
  __syncthreads();
  {
    float a0 = 0.f, a1 = 0.f;
    #pragma unroll
    for (int c4 = 0; c4 < 16; ++c4){
      float4 dv = *(const float4*)&zd[c4*4];
      a0 += WT[(64 + c4*4 + 0)*64 + j]*dv.x;
      a1 += WT[(64 + c4*4 + 1)*64 + j]*dv.y;
      a0 += WT[(64 + c4*4 + 2)*64 + j]*dv.z;
      a1 += WT[(64 + c4*4 + 3)*64 + j]*dv.w;
    }
    bconst += a0 + a1;
  }
  for (int t = 0; t < 64; ++t){
    if (g < 2){
      float a0 = 0.f, a1 = 0.f;
      #pragma unroll
      for (int c4 = 0; c4 < 16; ++c4){
        float4 pv = *(const float4*)&zp[c4*4];
        a0 += wv[c4*4+0]*pv.x; a1 += wv[c4*4+1]*pv.y;
        a0 += wv[c4*4+2]*pv.z; a1 += wv[c4*4+3]*pv.w;
      }
      float v = sigm(bconst + a0 + a1);
      if (g == 0) rz[j]   = v*zp[j];
      else        ubuf[j] = v;
    }
    __syncthreads();
    if (g == 2){
      float a0 = 0.f, a1 = 0.f;
      #pragma unroll
      for (int c4 = 0; c4 < 16; ++c4){
        float4 rv = *(const float4*)&rz[c4*4];
        a0 += wv[c4*4+0]*rv.x; a1 += wv[c4*4+1]*rv.y;
        a0 += wv[c4*4+2]*rv.z; a1 += wv[c4*4+3]*rv.w;
      }
      float cc = tanhf(bconst + a0 + a1);
      float u  = ubuf[j];
      float zt = (1.0f - u)*zp[j] + u*cc;
      zs[(size_t)s*4096 + t*64 + j] = zt;
      zp[j] = zt;
    }
    __syncthreads();
  }
}

// ---------------- host launch ----------------
extern "C" void kernel_launch(void* const* d_in, const int* in_sizes, int n_in,
                              void* d_out, int out_size, void* d_ws, size_t ws_size,
                              hipStream_t stream){
  static const int Vl[5] = {2048, 1024, 512, 256, 128};
  static const int El[5] = {12288, 6144, 3072, 1536, 768};
  static const int VO[4] = {0, 2048, 3072, 3584};
  static const int EO[4] = {0, 12288, 18432, 21504};

  const float* xin = (const float*)d_in[0];
  const int*   ei[4]; const float* ea[4];
  for (int l = 0; l < 4; ++l){ ei[l] = (const int*)d_in[1 + 2*l]; ea[l] = (const float*)d_in[2 + 2*l]; }
  const float* Psrc[8] = {(const float*)d_in[11], (const float*)d_in[12], (const float*)d_in[13], (const float*)d_in[14],
                          (const float*)d_in[15], (const float*)d_in[16], (const float*)d_in[17], (const float*)d_in[18]};
  const float* conv_w[4]   = {(const float*)d_in[19], (const float*)d_in[20], (const float*)d_in[21], (const float*)d_in[22]};
  const float* deconv_w[4] = {(const float*)d_in[23], (const float*)d_in[24], (const float*)d_in[25], (const float*)d_in[26]};
  const float* fce1_w = (const float*)d_in[27]; const float* fce1_b = (const float*)d_in[28];
  const float* fce2_w = (const float*)d_in[29]; const float* fce2_b = (const float*)d_in[30];
  const float* fcd3_w = (const float*)d_in[31]; const float* fcd3_b = (const float*)d_in[32];
  const float* fcd4_w = (const float*)d_in[33]; const float* fcd4_b = (const float*)d_in[34];
  const float* dom_Wih = (const float*)d_in[35]; const float* dom_Whh = (const float*)d_in[36];
  const float* dom_bih = (const float*)d_in[37]; const float* dom_bhh = (const float*)d_in[38];
  const float* dom_aggw = (const float*)d_in[39]; const float* dom_aggb = (const float*)d_in[40];
  const float* ini_Wih = (const float*)d_in[41]; const float* ini_Whh = (const float*)d_in[42];
  const float* ini_bih = (const float*)d_in[43]; const float* ini_bhh = (const float*)d_in[44];
  const float* ini_aggw = (const float*)d_in[45]; const float* ini_aggb = (const float*)d_in[46];
  const float* tr_Wr = (const float*)d_in[47]; const float* tr_br = (const float*)d_in[48];
  const float* tr_Wu = (const float*)d_in[49]; const float* tr_bu = (const float*)d_in[50];
  const float* tr_Wc = (const float*)d_in[51]; const float* tr_bc = (const float*)d_in[52];

  // ---- carve workspace ----
  char* wsp = (char*)d_ws;
  size_t off = 0;
  auto carve = [&](size_t bytes) -> void* {
    void* p = wsp + off;
    off = (off + bytes + 255) & ~(size_t)255;
    return p;
  };
  const size_t BUFCAP = (size_t)NB*2048*8*64;
  float* bufA = (float*)carve(BUFCAP*4);   // bufA+bufB together hold GI (S*T x 512 bf16) during latent phase
  float* bufB = (float*)carve(BUFCAP*4);
  void* webt = carve((size_t)NB*1024*1024*2 + 1024);
  float*  We = (float*)webt;
  ushort* BT = (ushort*)webt;
  ushort* xT = (ushort*)webt;
  ushort* WeTb = (ushort*)carve((size_t)1536*64*32*2 + 1024);
  ushort* embB2 = (ushort*)carve((size_t)1024*64*64*2);
  float* zD   = (float*)carve((size_t)NB*128*64*4);
  float* z0   = (float*)carve((size_t)NB*128*64*4);
  float* domWhhT = (float*)carve(12288*4);
  float* iniWhhT = (float*)carve(12288*4);
  float* domAggT = (float*)carve(4096*4);
  float* iniAggT = (float*)carve(4096*4);
  float* trWrT   = (float*)carve(8192*4);
  float* trWuT   = (float*)carve(8192*4);
  float* trWcT   = (float*)carve(8192*4);
  ushort* WihPad2 = (ushort*)carve(512*64*2);   // rows 0-255 dom, 256-511 ini (contiguous)
  ushort* Wfce1b = (ushort*)carve(8192*2);
  ushort* Wfce2b = (ushort*)carve(8192*2);
  ushort* Wfcd3b = (ushort*)carve(8192*2);
  ushort* Wfcd4b = (ushort*)carve(8192*2);
  static const int PM[8] = {1024, 512, 256, 128, 256, 512, 1024, 2048};
  static const int PK[8] = {2048, 1024, 512, 256, 128, 256, 512, 1024};
  ushort* Pb[8];
  for (int i = 0; i < 8; ++i) Pb[i] = (ushort*)carve((size_t)PM[i]*PK[i]*2);
  int* deg_all    = (int*)carve(TOTV*4);
  int* cursor_all = (int*)carve(TOTV*4);
  int* rowptr_all = (int*)carve((TOTV + 4)*4);
  int* elist_all  = (int*)carve(TOTE*4);
  (void)ws_size; (void)in_sizes; (void)n_in; (void)out_size;

  // ---- fused weight prep (one dispatch) ----
  PrepTasks T;
  int nt = 0;
  auto addT = [&](const float* s, void* d, int R, int C, int ty){
    T.src[nt] = s; T.dst[nt] = d; T.R[nt] = R; T.C[nt] = C; T.type[nt] = ty; ++nt;
  };
  addT(dom_Whh, domWhhT, 192, 64, 0);
  addT(ini_Whh, iniWhhT, 192, 64, 0);
  addT(dom_aggw, domAggT, 64, 64, 0);
  addT(ini_aggw, iniAggT, 64, 64, 0);
  addT(tr_Wr, trWrT, 64, 128, 0);
  addT(tr_Wu, trWuT, 64, 128, 0);
  addT(tr_Wc, trWcT, 64, 128, 0);
  addT(dom_Wih, WihPad2, 256, 64, 1);
  addT(ini_Wih, WihPad2 + 256*64, 256, 64, 1);
  addT(fce1_w, Wfce1b, 128, 64, 2);
  addT(fce2_w, Wfce2b, 64, 128, 2);
  addT(fcd3_w, Wfcd3b, 128, 64, 2);
  addT(fcd4_w, Wfcd4b, 64, 128, 2);
  for (int i = 0; i < 8; ++i) addT(Psrc[i], Pb[i], PM[i], PK[i], 2);
  T.ntask = nt;
  T.blk0[0] = 0;
  for (int i = 0; i < nt; ++i) T.blk0[i+1] = T.blk0[i] + (T.R[i]*T.C[i] + 255)/256;
  prep_all<<<T.blk0[nt], 256, 0, stream>>>(T);

  // ---- parallel CSR build ----
  const int* dsts[4] = {ei[0] + El[0], ei[1] + El[1], ei[2] + El[2], ei[3] + El[3]};
  csr_zero<<<(TOTV + 255)/256, 256, 0, stream>>>(deg_all);
  csr_deg <<<(TOTE + 255)/256, 256, 0, stream>>>(dsts[0], dsts[1], dsts[2], dsts[3], deg_all);
  csr_scan<<<4, 1024, 0, stream>>>(deg_all, rowptr_all, cursor_all);
  csr_fill<<<(TOTE + 255)/256, 256, 0, stream>>>(dsts[0], dsts[1], dsts[2], dsts[3], cursor_all, elist_all);
  csr_sort<<<(TOTV + 255)/256, 256, 0, stream>>>(rowptr_all, elist_all);

  // ---- stage helpers ----
  auto gconv = [&](const float* in, float* out, int l, const float* Wb, int Ci, int Co){
    int CiCo = Ci*Co;
    int tot = El[l]*CiCo;
    edge_we_kernel<<<(tot + 255)/256, 256, 0, stream>>>(ea[l], Wb, We, El[l], CiCo);
    int nblk = NB*Vl[l];
    const int* rp = rowptr_all + VO[l] + l;
    const int* el = elist_all + EO[l];
    #define GCASE(CI,CO) if (Ci==CI && Co==CO) gconv2_kernel<CI,CO><<<nblk, 256, 0, stream>>>(in, We, ei[l], rp, el, out, Vl[l]);
    GCASE(1,8)  GCASE(8,16)  GCASE(16,8)  GCASE(8,1)
    #undef GCASE
  };
  auto gconv_m = [&](const float* in, float* out, int l, const float* Wb, int Ci, int Co){
    int S = NB*Vl[l];
    int CiP = (Ci < 32) ? 32 : Ci;
    if (Ci == 16)      xpose_bf16<16,32><<<S, 256, 0, stream>>>(in, xT);
    else if (Ci == 32) xpose_bf16<32,32><<<S, 256, 0, stream>>>(in, xT);
    else               xpose_bf16<64,64><<<S, 256, 0, stream>>>(in, xT);
    if (Ci == 16 && Co == 32)      edge_weT2<16,32,32><<<El[l], 256, 0, stream>>>(ea[l], Wb, WeTb);
    else if (Ci == 32 && Co == 64) edge_weT2<32,64,32><<<El[l], 256, 0, stream>>>(ea[l], Wb, WeTb);
    else if (Ci == 64 && Co == 32) edge_weT2<64,32,64><<<El[l], 256, 0, stream>>>(ea[l], Wb, WeTb);
    else if (Ci == 32 && Co == 16) edge_weT2<32,16,32><<<El[l], 256, 0, stream>>>(ea[l], Wb, WeTb);
    const int* rp = rowptr_all + VO[l] + l;
    const int* el = elist_all + EO[l];
    #define GMC(CIP,CO) if (CiP==CIP && Co==CO) gconv_mfma4<CIP,CO><<<S, 256, 0, stream>>>(xT, WeTb, ei[l], rp, el, out, Vl[l]);
    GMC(32,32) GMC(32,64) GMC(64,32) GMC(32,16)
    #undef GMC
  };
  auto pool2 = [&](int pi, const float* hin, float* out, int M, int K, int NN){
    dim3 tg(NN/64, K/64, NB);
    transp_bf16<<<tg, 256, 0, stream>>>(hin, BT, K, NN);
    dim3 g(NN/64, M/64, NB);
    pool_mfma64<0><<<g, 256, 0, stream>>>(Pb[pi], BT, (void*)out, M, K, NN);
  };

  // ---- encoder ----
  gconv(xin,  bufA, 0, conv_w[0], 1, 8);
  pool2(0, bufA, bufB, 1024, 2048, 512);
  gconv(bufB, bufA, 1, conv_w[1], 8, 16);
  pool2(1, bufA, bufB, 512, 1024, 1024);
  gconv_m(bufB, bufA, 2, conv_w[2], 16, 32);
  pool2(2, bufA, bufB, 256, 512, 2048);
  gconv_m(bufB, bufA, 3, conv_w[3], 32, 64);
  pool2(3, bufA, bufB, 128, 256, 4096);

  // fused fce1+fce2: (s,64,t) fp32 -> emb (s,t,64) bf16 (ELU then tanh)
  pw2_mfma<64,128,64,1,2,0,1><<<1024, 256, 0, stream>>>(bufB, Wfce1b, fce1_b, Wfce2b, fce2_b, embB2);

  // ---- latent ----
  // merged GI GEMM: out (65536, 512) bf16 into bufA||bufB (contiguous 67 MB)
  dim3 gg(8, 1024, 1);
  pool_mfma64<1><<<gg, 256, 0, stream>>>(embB2, WihPad2, (void*)bufA, 65536, 64, 512);
  gru3m_kernel<<<2*NB*128, 192, 0, stream>>>((const ushort*)bufA,
      domWhhT, iniWhhT, dom_bih, dom_bhh, domAggT, dom_aggb,
      ini_bih, ini_bhh, iniAggT, ini_aggb, zD, z0, NB*128);
  trans2_kernel<<<NB*128, 192, 0, stream>>>(z0, zD, trWrT, trWuT, trWcT, tr_br, tr_bu, tr_bc, bufA);

  // ---- decoder ----
  pw2_mfma<64,128,64,1,1,1,0><<<1024, 256, 0, stream>>>(bufA, Wfcd3b, fcd3_b, Wfcd4b, fcd4_b, bufB);
  pool2(4, bufB, bufA, 256, 128, 4096);
  gconv_m(bufA, bufB, 3, deconv_w[0], 64, 32);
  pool2(5, bufB, bufA, 512, 256, 2048);
  gconv_m(bufA, bufB, 2, deconv_w[1], 32, 16);
  pool2(6, bufB, bufA, 1024, 512, 1024);
  gconv(bufA, bufB, 1, deconv_w[2], 16, 8);
  pool2(7, bufB, bufA, 2048, 1024, 512);
  gconv(bufA, (float*)d_out, 0, deconv_w[3], 8, 1);
}

// Round 17
// 741.368 us; speedup vs baseline: 1.0957x; 1.0675x over previous
//
#include <hip/hip_runtime.h>

#define NB 8   // batch
#define TT 64  // time

typedef __attribute__((ext_vector_type(8))) short bf16x8_t;
typedef __attribute__((ext_vector_type(4))) float f32x4_t;

__device__ __forceinline__ float sigm(float x){ return 1.0f/(1.0f+expf(-x)); }
__device__ __forceinline__ float eluf(float x){ return x>0.0f ? x : expm1f(x); }
__device__ __forceinline__ ushort f2bf(float f){
  uint u = __float_as_uint(f);
  return (ushort)((u + 0x7FFFu + ((u >> 16) & 1u)) >> 16);   // RNE
}
__device__ __forceinline__ float bf2f(ushort u){
  return __uint_as_float(((uint)u) << 16);
}

// CSR fused-level geometry (levels 0..3)
__device__ __constant__ int c_VL[4] = {2048, 1024, 512, 256};
__device__ __constant__ int c_VO[4] = {0, 2048, 3072, 3584};
__device__ __constant__ int c_EO[4] = {0, 12288, 18432, 21504};
#define TOTV 3840
#define TOTE 23040

// ---------------- fused weight prep ----------------
#define NPREP 21
struct PrepTasks {
  const float* src[NPREP];
  void* dst[NPREP];
  int R[NPREP], C[NPREP];
  int type[NPREP];   // 0: fp32 transpose; 1: pad_wih; 2: bf16 convert
  int blk0[NPREP + 1];
  int ntask;
};

__global__ __launch_bounds__(256) void prep_all(PrepTasks T){
  int b = blockIdx.x;
  int t = 0;
  while (t + 1 < T.ntask && b >= T.blk0[t+1]) ++t;
  int idx = (b - T.blk0[t])*256 + threadIdx.x;
  int n = T.R[t]*T.C[t];
  if (idx >= n) return;
  int ty = T.type[t];
  if (ty == 0){
    int C = T.C[t];
    int r = idx / C, c = idx - r*C;
    ((float*)T.dst[t])[c*T.R[t] + r] = T.src[t][idx];
  } else if (ty == 1){
    int r = idx >> 6;
    ((ushort*)T.dst[t])[idx] = (r < 192) ? f2bf(T.src[t][idx]) : (ushort)0;
  } else {
    ((ushort*)T.dst[t])[idx] = f2bf(T.src[t][idx]);
  }
}

// per-vertex activation transpose: in (S, Ci, 64) fp32 -> out (S, 64, CiP) bf16
template<int Ci, int CiP>
__global__ __launch_bounds__(256) void xpose_bf16(const float* __restrict__ in, ushort* __restrict__ out){
  __shared__ float tile[Ci][65];
  int s = blockIdx.x, tid = threadIdx.x;
  const float* ip = in + (size_t)s*Ci*64;
  for (int i = tid; i < Ci*64; i += 256) tile[i>>6][i&63] = ip[i];
  __syncthreads();
  ushort* op = out + (size_t)s*64*CiP;
  for (int i = tid; i < 64*CiP; i += 256){
    int t = i / CiP, ci = i - t*CiP;
    op[i] = (ci < Ci) ? f2bf(tile[ci][t]) : (ushort)0;
  }
}

// ---------------- parallel CSR build ----------------
__global__ void csr_zero(int* __restrict__ deg_all){
  int i = blockIdx.x*256 + threadIdx.x;
  if (i < TOTV) deg_all[i] = 0;
}

__global__ void csr_deg(const int* __restrict__ d0, const int* __restrict__ d1,
                        const int* __restrict__ d2, const int* __restrict__ d3,
                        int* __restrict__ deg_all){
  int idx = blockIdx.x*256 + threadIdx.x;
  if (idx >= TOTE) return;
  int l = (idx < 12288) ? 0 : (idx < 18432) ? 1 : (idx < 21504) ? 2 : 3;
  int e = idx - c_EO[l];
  const int* dl = (l==0)?d0:(l==1)?d1:(l==2)?d2:d3;
  atomicAdd(&deg_all[c_VO[l] + dl[e]], 1);
}

__global__ __launch_bounds__(1024) void csr_scan(const int* __restrict__ deg_all,
                                                 int* __restrict__ rowptr_all,
                                                 int* __restrict__ cursor_all){
  __shared__ int a[2048], b[2048];
  int l = blockIdx.x;
  int Vv = c_VL[l], vo = c_VO[l], eo = c_EO[l];
  int tid = threadIdx.x;
  for (int i = tid; i < 2048; i += 1024) a[i] = (i < Vv) ? deg_all[vo + i] : 0;
  __syncthreads();
  int* s = a; int* d = b;
  for (int off = 1; off < 2048; off <<= 1){
    for (int i = tid; i < 2048; i += 1024) d[i] = s[i] + ((i >= off) ? s[i-off] : 0);
    __syncthreads();
    int* t = s; s = d; d = t;
  }
  int rbase = vo + l;
  for (int i = tid; i < Vv; i += 1024){
    int excl = (i == 0) ? 0 : s[i-1];
    rowptr_all[rbase + i] = excl;
    cursor_all[vo + i]    = eo + excl;
  }
  if (tid == 0) rowptr_all[rbase + Vv] = s[2047];
}

__global__ void csr_fill(const int* __restrict__ d0, const int* __restrict__ d1,
                         const int* __restrict__ d2, const int* __restrict__ d3,
                         int* __restrict__ cursor_all, int* __restrict__ elist_all){
  int idx = blockIdx.x*256 + threadIdx.x;
  if (idx >= TOTE) return;
  int l = (idx < 12288) ? 0 : (idx < 18432) ? 1 : (idx < 21504) ? 2 : 3;
  int e = idx - c_EO[l];
  const int* dl = (l==0)?d0:(l==1)?d1:(l==2)?d2:d3;
  int p = atomicAdd(&cursor_all[c_VO[l] + dl[e]], 1);
  elist_all[p] = e;
}

__global__ void csr_sort(const int* __restrict__ rowptr_all, int* __restrict__ elist_all){
  int idx = blockIdx.x*256 + threadIdx.x;
  if (idx >= TOTV) return;
  int l = (idx < 2048) ? 0 : (idx < 3072) ? 1 : (idx < 3584) ? 2 : 3;
  int v = idx - c_VO[l];
  int rbase = c_VO[l] + l, eo = c_EO[l];
  int s = eo + rowptr_all[rbase + v], epos = eo + rowptr_all[rbase + v + 1];
  for (int i = s + 1; i < epos; ++i){
    int key = elist_all[i];
    int j = i - 1;
    while (j >= s && elist_all[j] > key){ elist_all[j+1] = elist_all[j]; --j; }
    elist_all[j+1] = key;
  }
}

// B-spline edge weights (fp32, vector gconv levels 0/1)
__global__ void edge_we_kernel(const float* __restrict__ attr, const float* __restrict__ Wb,
                               float* __restrict__ We, int E, int CiCo){
  int idx = blockIdx.x*256 + threadIdx.x;
  if (idx >= E*CiCo) return;
  int e = idx / CiCo, r = idx - e*CiCo;
  float f[3]; int i0[3];
  #pragma unroll
  for (int d = 0; d < 3; ++d){
    float p  = attr[e*3+d]*2.0f;
    float fl = fminf(fmaxf(floorf(p), 0.0f), 1.0f);
    i0[d] = (int)fl;
    f[d]  = p - fl;
  }
  float acc = 0.0f;
  #pragma unroll
  for (int c0 = 0; c0 < 2; ++c0){
    float w0 = c0 ? f[0] : 1.0f - f[0];
    #pragma unroll
    for (int c1 = 0; c1 < 2; ++c1){
      float w1 = c1 ? f[1] : 1.0f - f[1];
      #pragma unroll
      for (int c2 = 0; c2 < 2; ++c2){
        float w2 = c2 ? f[2] : 1.0f - f[2];
        int flat = (i0[0]+c0)*9 + (i0[1]+c1)*3 + (i0[2]+c2);
        acc += w0*w1*w2 * Wb[flat*CiCo + r];
      }
    }
  }
  We[idx] = acc;
}

// B-spline -> transposed bf16 WeT[e, co, ciP]
template<int Ci, int Co, int CiP>
__global__ __launch_bounds__(256) void edge_weT2(
    const float* __restrict__ attr, const float* __restrict__ Wb,
    ushort* __restrict__ WeT){
  __shared__ float s[Ci][Co + 1];
  int e = blockIdx.x, tid = threadIdx.x;
  float f[3]; int i0[3];
  #pragma unroll
  for (int d = 0; d < 3; ++d){
    float p  = attr[e*3+d]*2.0f;
    float fl = fminf(fmaxf(floorf(p), 0.0f), 1.0f);
    i0[d] = (int)fl;
    f[d]  = p - fl;
  }
  float w[8]; int fl8[8];
  #pragma unroll
  for (int c0 = 0; c0 < 2; ++c0)
    #pragma unroll
    for (int c1 = 0; c1 < 2; ++c1)
      #pragma unroll
      for (int c2 = 0; c2 < 2; ++c2){
        int k = c0*4 + c1*2 + c2;
        w[k] = (c0 ? f[0] : 1.0f - f[0]) * (c1 ? f[1] : 1.0f - f[1]) * (c2 ? f[2] : 1.0f - f[2]);
        fl8[k] = (i0[0]+c0)*9 + (i0[1]+c1)*3 + (i0[2]+c2);
      }
  constexpr int CiCo = Ci*Co;
  for (int r = tid; r < CiCo; r += 256){
    float acc = 0.0f;
    #pragma unroll
    for (int k = 0; k < 8; ++k) acc += w[k]*Wb[fl8[k]*CiCo + r];
    s[r/Co][r - (r/Co)*Co] = acc;
  }
  __syncthreads();
  ushort* op = WeT + (size_t)e*(Co*CiP);
  for (int r2 = tid; r2 < Co*CiP; r2 += 256){
    int co = r2 / CiP, ci = r2 - co*CiP;
    op[r2] = (ci < Ci) ? f2bf(s[ci][co]) : (ushort)0;
  }
}

// ---------------- graph conv (vector path, levels 0/1) ----------------
template<int Ci, int Co>
__global__ __launch_bounds__(256) void gconv2_kernel(
    const float* __restrict__ x, const float* __restrict__ We,
    const int* __restrict__ src_arr, const int* __restrict__ rowptr,
    const int* __restrict__ elist, float* __restrict__ out, int V){
  constexpr int CiCo = Ci*Co;
  __shared__ float ws[4][CiCo];
  __shared__ float red[Co*64];
  int blk = blockIdx.x;
  int n = blk / V, v = blk - n*V;
  int tid = threadIdx.x;
  int w = tid >> 6, lane = tid & 63;
  int rs = rowptr[v], re = rowptr[v+1];
  float acc[Co];
  #pragma unroll
  for (int i = 0; i < Co; ++i) acc[i] = 0.0f;

  for (int q = rs + w; q < re; q += 4){
    int e   = elist[q];
    int src = src_arr[e];
    const float* wsrc = We + (size_t)e*CiCo;
    #pragma unroll
    for (int i = lane; i < CiCo; i += 64) ws[w][i] = wsrc[i];
    __builtin_amdgcn_s_waitcnt(0);
    const float* xp = x + ((size_t)(n*V + src))*(Ci*64) + lane;
    #pragma unroll 4
    for (int ci = 0; ci < Ci; ++ci){
      float xv = xp[(size_t)ci*64];
      if constexpr (Co >= 4){
        #pragma unroll
        for (int co = 0; co < Co; co += 4){
          float4 wv = *(const float4*)&ws[w][ci*Co + co];
          acc[co+0] += wv.x*xv;
          acc[co+1] += wv.y*xv;
          acc[co+2] += wv.z*xv;
          acc[co+3] += wv.w*xv;
        }
      } else {
        #pragma unroll
        for (int co = 0; co < Co; ++co) acc[co] += ws[w][ci*Co + co]*xv;
      }
    }
  }

  if (w == 0){
    #pragma unroll
    for (int co = 0; co < Co; ++co) red[co*64 + lane] = acc[co];
  }
  __syncthreads();
  #pragma unroll
  for (int ww = 1; ww < 4; ++ww){
    if (w == ww){
      #pragma unroll
      for (int co = 0; co < Co; ++co) red[co*64 + lane] += acc[co];
    }
    __syncthreads();
  }
  float scale = 1.0f / fmaxf((float)(re - rs), 1.0f);
  size_t ob = ((size_t)(n*V + v))*(Co*64);
  for (int co = w; co < Co; co += 4)
    out[ob + (size_t)co*64 + lane] = eluf(red[co*64 + lane]*scale);
}

// ---------------- graph conv (MFMA path, levels 2/3), wave-split edges ----------------
template<int CiP, int Co>
__global__ __launch_bounds__(256, 4) void gconv_mfma4(
    const ushort* __restrict__ xT, const ushort* __restrict__ WeT,
    const int* __restrict__ src_arr, const int* __restrict__ rowptr,
    const int* __restrict__ elist, float* __restrict__ out, int V){
  constexpr int MT = Co/16, KT = CiP/32;
  __shared__ int2 es[64];
  __shared__ float red[Co*64];
  int bid = blockIdx.x;
  int r8 = bid & 7, q0 = bid >> 3;
  int n = q0 & 7;
  int v = ((q0 >> 3) << 3) | r8;
  int tid = threadIdx.x;
  int w = tid >> 6, lane = tid & 63;
  int l15 = lane & 15, g = lane >> 4;
  int rs = rowptr[v], re = rowptr[v+1];
  int deg = re - rs;
  int cnt0 = (deg < 64) ? deg : 64;
  if (tid < cnt0){
    int e = elist[rs + tid];
    es[tid] = make_int2(e, src_arr[e]);
  }
  __syncthreads();
  f32x4_t acc[MT][4];
  #pragma unroll
  for (int m = 0; m < MT; ++m)
    #pragma unroll
    for (int tt = 0; tt < 4; ++tt) acc[m][tt] = (f32x4_t){0.f,0.f,0.f,0.f};
  for (int q = w; q < deg; q += 4){
    int e, src;
    if (q < 64){ e = es[q].x; src = es[q].y; }
    else { e = elist[rs + q]; src = src_arr[e]; }
    const ushort* xp = xT + ((size_t)(n*V + src))*(64*CiP) + (size_t)l15*CiP + g*8;
    const ushort* wp = WeT + (size_t)e*(Co*CiP) + (size_t)l15*CiP + g*8;
    #pragma unroll
    for (int kt = 0; kt < KT; ++kt){
      bf16x8_t bfrag[4];
      #pragma unroll
      for (int tt = 0; tt < 4; ++tt)
        bfrag[tt] = *(const bf16x8_t*)(xp + (size_t)tt*16*CiP + kt*32);
      #pragma unroll
      for (int m = 0; m < MT; ++m){
        bf16x8_t afrag = *(const bf16x8_t*)(wp + (size_t)m*16*CiP + kt*32);
        #pragma unroll
        for (int tt = 0; tt < 4; ++tt)
          acc[m][tt] = __builtin_amdgcn_mfma_f32_16x16x32_bf16(afrag, bfrag[tt], acc[m][tt], 0, 0, 0);
      }
    }
  }
  if (w == 0){
    #pragma unroll
    for (int m = 0; m < MT; ++m)
      #pragma unroll
      for (int tt = 0; tt < 4; ++tt)
        #pragma unroll
        for (int r = 0; r < 4; ++r)
          red[(m*16 + g*4 + r)*64 + tt*16 + l15] = acc[m][tt][r];
  }
  __syncthreads();
  #pragma unroll
  for (int ww = 1; ww < 4; ++ww){
    if (w == ww){
      #pragma unroll
      for (int m = 0; m < MT; ++m)
        #pragma unroll
        for (int tt = 0; tt < 4; ++tt)
          #pragma unroll
          for (int r = 0; r < 4; ++r)
            red[(m*16 + g*4 + r)*64 + tt*16 + l15] += acc[m][tt][r];
    }
    __syncthreads();
  }
  float scale = 1.0f / fmaxf((float)deg, 1.0f);
  size_t ob = ((size_t)(n*V + v))*(Co*64);
  for (int i = tid; i < Co*64; i += 256)
    out[ob + i] = eluf(red[i]*scale);
}

// ---------------- 64x64-tile MFMA GEMM, bf16 BT operand (GI GEMM only) ----------------
template<int OUTBF>
__global__ __launch_bounds__(256) void pool_mfma64(
    const ushort* __restrict__ A, const ushort* __restrict__ BT, void* __restrict__ Cout,
    int M, int K, int NN){
  __shared__ ushort As[64*40];
  __shared__ ushort Bs[64*40];
  char* Asb = (char*)As; char* Bsb = (char*)Bs;
  int tid = threadIdx.x;
  int wv = tid >> 6, lane = tid & 63;
  int g = lane >> 4, l15 = lane & 15;
  int wr = wv >> 1, wc = wv & 1;
  int m0 = blockIdx.y*64, n0 = blockIdx.x*64;
  const ushort* Bp = BT + (size_t)blockIdx.z*((size_t)NN*K);
  f32x4_t acc[2][2];
  #pragma unroll
  for (int i = 0; i < 2; ++i)
    #pragma unroll
    for (int j = 0; j < 2; ++j) acc[i][j] = (f32x4_t){0.f,0.f,0.f,0.f};
  int srow = tid >> 2, slot = tid & 3;
  int wbo = srow*80 + slot*16;
  const ushort* gA = A  + (size_t)(m0+srow)*K + slot*8;
  const ushort* gB = Bp + (size_t)(n0+srow)*K + slot*8;
  for (int k0 = 0; k0 < K; k0 += 32){
    uint4 va = *(const uint4*)(gA + k0);
    uint4 vb = *(const uint4*)(gB + k0);
    __syncthreads();
    *(uint4*)(Asb + wbo) = va;
    *(uint4*)(Bsb + wbo) = vb;
    __syncthreads();
    bf16x8_t af[2], bfr[2];
    #pragma unroll
    for (int f = 0; f < 2; ++f){
      af[f]  = *(const bf16x8_t*)(Asb + (wr*32 + f*16 + l15)*80 + g*16);
      bfr[f] = *(const bf16x8_t*)(Bsb + (wc*32 + f*16 + l15)*80 + g*16);
    }
    #pragma unroll
    for (int fm = 0; fm < 2; ++fm)
      #pragma unroll
      for (int fn = 0; fn < 2; ++fn)
        acc[fm][fn] = __builtin_amdgcn_mfma_f32_16x16x32_bf16(af[fm], bfr[fn], acc[fm][fn], 0, 0, 0);
  }
  #pragma unroll
  for (int fm = 0; fm < 2; ++fm){
    int row = m0 + wr*32 + fm*16 + g*4;
    #pragma unroll
    for (int fn = 0; fn < 2; ++fn){
      int col = n0 + wc*32 + fn*16 + l15;
      if constexpr (OUTBF){
        ushort* Cb = (ushort*)Cout + (size_t)blockIdx.z*((size_t)M*NN);
        #pragma unroll
        for (int r = 0; r < 4; ++r)
          Cb[(size_t)(row + r)*NN + col] = f2bf(acc[fm][fn][r]);
      } else {
        float* Cf = (float*)Cout + (size_t)blockIdx.z*((size_t)M*NN);
        #pragma unroll
        for (int r = 0; r < 4; ++r)
          Cf[(size_t)(row + r)*NN + col] = acc[fm][fn][r];
      }
    }
  }
}

// ---------------- 64x64-tile MFMA GEMM, fp32 B in (K,NN) layout (pools; fused transpose) ----------------
// A: (M,K) bf16 row-major; B: (z, K, NN) fp32; C: (z, M, NN) fp32
__global__ __launch_bounds__(256) void pool_mfma64f(
    const ushort* __restrict__ A, const float* __restrict__ B, float* __restrict__ Cout,
    int M, int K, int NN){
  __shared__ ushort As[64*40];
  __shared__ ushort Bs[64*40];
  char* Asb = (char*)As; char* Bsb = (char*)Bs;
  int tid = threadIdx.x;
  int wv = tid >> 6, lane = tid & 63;
  int g = lane >> 4, l15 = lane & 15;
  int wr = wv >> 1, wc = wv & 1;
  int m0 = blockIdx.y*64, n0 = blockIdx.x*64;
  const float* Bp = B + (size_t)blockIdx.z*((size_t)K*NN);
  float* Cp = Cout + (size_t)blockIdx.z*((size_t)M*NN);
  f32x4_t acc[2][2];
  #pragma unroll
  for (int i = 0; i < 2; ++i)
    #pragma unroll
    for (int j = 0; j < 2; ++j) acc[i][j] = (f32x4_t){0.f,0.f,0.f,0.f};
  int srow = tid >> 2, slot = tid & 3;
  int wboA = srow*80 + slot*16;
  const ushort* gA = A + (size_t)(m0+srow)*K + slot*8;
  int bcol = tid & 63, bkg = tid >> 6;          // thread owns NN-col bcol, k-group bkg
  const float* gB = Bp + n0 + bcol;
  int wboB = bcol*80 + bkg*16;
  for (int k0 = 0; k0 < K; k0 += 32){
    uint4 va = *(const uint4*)(gA + k0);
    ushort bv[8];
    #pragma unroll
    for (int kk = 0; kk < 8; ++kk)
      bv[kk] = f2bf(gB[(size_t)(k0 + bkg*8 + kk)*NN]);   // per-kk: 256B coalesced across wave
    __syncthreads();
    *(uint4*)(Asb + wboA) = va;
    *(uint4*)(Bsb + wboB) = *(uint4*)bv;
    __syncthreads();
    bf16x8_t af[2], bfr[2];
    #pragma unroll
    for (int f = 0; f < 2; ++f){
      af[f]  = *(const bf16x8_t*)(Asb + (wr*32 + f*16 + l15)*80 + g*16);
      bfr[f] = *(const bf16x8_t*)(Bsb + (wc*32 + f*16 + l15)*80 + g*16);
    }
    #pragma unroll
    for (int fm = 0; fm < 2; ++fm)
      #pragma unroll
      for (int fn = 0; fn < 2; ++fn)
        acc[fm][fn] = __builtin_amdgcn_mfma_f32_16x16x32_bf16(af[fm], bfr[fn], acc[fm][fn], 0, 0, 0);
  }
  #pragma unroll
  for (int fm = 0; fm < 2; ++fm){
    int row = m0 + wr*32 + fm*16 + g*4;
    #pragma unroll
    for (int fn = 0; fn < 2; ++fn){
      int col = n0 + wc*32 + fn*16 + l15;
      #pragma unroll
      for (int r = 0; r < 4; ++r)
        Cp[(size_t)(row + r)*NN + col] = acc[fm][fn][r];
    }
  }
}

// ---------------- fused dual MFMA pointwise ----------------
template<int C, int O1, int O2, int ACT1, int ACT2, int INF, int OUTF>
__global__ __launch_bounds__(256) void pw2_mfma(
    const void* __restrict__ inv,
    const ushort* __restrict__ W1, const float* __restrict__ b1,
    const ushort* __restrict__ W2, const float* __restrict__ b2,
    void* __restrict__ outv){
  constexpr int CP = C + 8, O1P = O1 + 8;
  constexpr int MT1 = O1/16, KT1 = C/32;
  constexpr int MT2 = O2/16, KT2 = O1/32;
  __shared__ ushort XT[64*CP];
  __shared__ ushort YT[64*O1P];
  int s = blockIdx.x, tid = threadIdx.x;
  int w = tid >> 6, lane = tid & 63;
  int l15 = lane & 15, g = lane >> 4;
  if constexpr (INF == 0){
    const float* ip = (const float*)inv + (size_t)s*C*64;
    for (int i = tid; i < C*64; i += 256){ int c = i >> 6, t = i & 63; XT[t*CP + c] = f2bf(ip[i]); }
  } else {
    const float* ip = (const float*)inv + (size_t)s*64*C;
    for (int i = tid; i < C*64; i += 256){ int t = i / C, c = i - t*C; XT[t*CP + c] = f2bf(ip[i]); }
  }
  __syncthreads();
  int trow = w*16 + l15;
  {
    f32x4_t acc[MT1];
    #pragma unroll
    for (int m = 0; m < MT1; ++m) acc[m] = (f32x4_t){0.f,0.f,0.f,0.f};
    #pragma unroll
    for (int kt = 0; kt < KT1; ++kt){
      bf16x8_t bfrag = *(const bf16x8_t*)(&XT[trow*CP + kt*32 + g*8]);
      #pragma unroll
      for (int m = 0; m < MT1; ++m){
        bf16x8_t afrag = *(const bf16x8_t*)(W1 + (size_t)(m*16 + l15)*C + kt*32 + g*8);
        acc[m] = __builtin_amdgcn_mfma_f32_16x16x32_bf16(afrag, bfrag, acc[m], 0, 0, 0);
      }
    }
    #pragma unroll
    for (int m = 0; m < MT1; ++m){
      #pragma unroll
      for (int r = 0; r < 4; ++r){
        int o = m*16 + g*4 + r;
        float v = acc[m][r] + b1[o];
        v = (ACT1 == 1) ? eluf(v) : tanhf(v);
        YT[trow*O1P + o] = f2bf(v);
      }
    }
  }
  __syncthreads();
  {
    f32x4_t acc[MT2];
    #pragma unroll
    for (int m = 0; m < MT2; ++m) acc[m] = (f32x4_t){0.f,0.f,0.f,0.f};
    #pragma unroll
    for (int kt = 0; kt < KT2; ++kt){
      bf16x8_t bfrag = *(const bf16x8_t*)(&YT[trow*O1P + kt*32 + g*8]);
      #pragma unroll
      for (int m = 0; m < MT2; ++m){
        bf16x8_t afrag = *(const bf16x8_t*)(W2 + (size_t)(m*16 + l15)*O1 + kt*32 + g*8);
        acc[m] = __builtin_amdgcn_mfma_f32_16x16x32_bf16(afrag, bfrag, acc[m], 0, 0, 0);
      }
    }
    if constexpr (OUTF == 0){
      float* op = (float*)outv + (size_t)s*O2*64;
      #pragma unroll
      for (int m = 0; m < MT2; ++m){
        #pragma unroll
        for (int r = 0; r < 4; ++r){
          int o = m*16 + g*4 + r;
          float v = acc[m][r] + b2[o];
          v = (ACT2 == 1) ? eluf(v) : tanhf(v);
          op[(size_t)o*64 + trow] = v;
        }
      }
    } else {
      constexpr int O2P = O2 + 8;
      #pragma unroll
      for (int m = 0; m < MT2; ++m){
        #pragma unroll
        for (int r = 0; r < 4; ++r){
          int o = m*16 + g*4 + r;
          float v = acc[m][r] + b2[o];
          v = (ACT2 == 1) ? eluf(v) : tanhf(v);
          XT[trow*O2P + o] = f2bf(v);
        }
      }
      __syncthreads();
      ushort* op = (ushort*)outv + (size_t)s*64*O2;
      for (int i = tid; i < 64*O2; i += 256){
        int t = i / O2, o = i - t*O2;
        op[i] = XT[t*O2P + o];
      }
    }
  }
}

// ---------------- merged GRU scans (dom + ini), gate-per-wave; GI stride 512 ----------------
__global__ __launch_bounds__(192) void gru3m_kernel(
    const ushort* __restrict__ GI,
    const float* __restrict__ WhhT_d, const float* __restrict__ WhhT_i,
    const float* __restrict__ bih_d, const float* __restrict__ bhh_d,
    const float* __restrict__ aggT_d, const float* __restrict__ aggb_d,
    const float* __restrict__ bih_i, const float* __restrict__ bhh_i,
    const float* __restrict__ aggT_i, const float* __restrict__ aggb_i,
    float* __restrict__ zD, float* __restrict__ z0, int S){
  __shared__ float hsh[64];
  __shared__ float rbuf[64];
  __shared__ float zbuf[64];
  int bid = blockIdx.x;
  bool dom = (bid < S);
  int s = dom ? bid : bid - S;
  int TS = dom ? 64 : 16;
  const float* WhhT  = dom ? WhhT_d : WhhT_i;
  const float* bih   = dom ? bih_d  : bih_i;
  const float* bhh   = dom ? bhh_d  : bhh_i;
  const float* aggT  = dom ? aggT_d : aggT_i;
  const float* aggb  = dom ? aggb_d : aggb_i;
  float* zout        = dom ? zD     : z0;
  int tid = threadIdx.x;
  int g = tid >> 6, j = tid & 63;
  if (tid < 64) hsh[tid] = 0.0f;
  float whh[64];
  #pragma unroll
  for (int c = 0; c < 64; ++c) whh[c] = WhhT[c*192 + tid];
  float b_i = bih[tid], b_h = bhh[tid];
  const ushort* gp = GI + (size_t)s*64*512 + (dom ? 0 : 256) + tid;
  float gi_cur = b_i + bf2f(gp[0]);
  __syncthreads();
  for (int t = 0; t < TS; ++t){
    ushort gnx = (t + 1 < TS) ? gp[(size_t)(t+1)*512] : (ushort)0;
    float gh0 = 0.f, gh1 = 0.f;
    #pragma unroll
    for (int c4 = 0; c4 < 16; ++c4){
      float4 hv = *(const float4*)&hsh[c4*4];
      gh0 += whh[c4*4+0]*hv.x; gh1 += whh[c4*4+1]*hv.y;
      gh0 += whh[c4*4+2]*hv.z; gh1 += whh[c4*4+3]*hv.w;
    }
    float gh = b_h + gh0 + gh1;
    if (g == 0)      rbuf[j] = sigm(gi_cur + gh);
    else if (g == 1) zbuf[j] = sigm(gi_cur + gh);
    __syncthreads();
    if (g == 2){
      float gg = tanhf(gi_cur + rbuf[j]*gh);
      float z  = zbuf[j];
      hsh[j] = (1.0f - z)*gg + z*hsh[j];
    }
    __syncthreads();
    gi_cur = b_i + bf2f(gnx);
  }
  if (tid < 64){
    float a = aggb[tid];
    #pragma unroll
    for (int c = 0; c < 64; ++c) a += aggT[c*64 + tid]*hsh[c];
    zout[(size_t)s*64 + tid] = tanhf(a);
  }
}

// ---------------- transition: gate-per-wave, register weights ----------------
__global__ __launch_bounds__(192) void trans2_kernel(
    const float* __restrict__ z0, const float* __restrict__ zD,
    const float* __restrict__ WrT, const float* __restrict__ WuT, const float* __restrict__ WcT,
    const float* __restrict__ br, const float* __restrict__ bu, const float* __restrict__ bc,
    float* __restrict__ zs){
  __shared__ float zp[64];
  __shared__ float zd[64];
  __shared__ float rz[64];
  __shared__ float ubuf[64];
  int s = blockIdx.x, tid = threadIdx.x;
  int g = tid >> 6, j = tid & 63;
  if (tid < 64){ zp[tid] = z0[(size_t)s*64 + tid]; zd[tid] = zD[(size_t)s*64 + tid]; }
  const float* WT = (g == 0) ? WrT : (g == 1) ? WuT : WcT;
  const float* bb = (g == 0) ? br  : (g == 1) ? bu  : bc;
  float wv[64];
  #pragma unroll
  for (int c = 0; c < 64; ++c) wv[c] = WT[c*64 + j];
  float bconst = bb[j];
  __syncthreads();
  {
    float a0 = 0.f, a1 = 0.f;
    #pragma unroll
    for (int c4 = 0; c4 < 16; ++c4){
      float4 dv = *(const float4*)&zd[c4*4];
      a0 += WT[(64 + c4*4 + 0)*64 + j]*dv.x;
      a1 += WT[(64 + c4*4 + 1)*64 + j]*dv.y;
      a0 += WT[(64 + c4*4 + 2)*64 + j]*dv.z;
      a1 += WT[(64 + c4*4 + 3)*64 + j]*dv.w;
    }
    bconst += a0 + a1;
  }
  for (int t = 0; t < 64; ++t){
    if (g < 2){
      float a0 = 0.f, a1 = 0.f;
      #pragma unroll
      for (int c4 = 0; c4 < 16; ++c4){
        float4 pv = *(const float4*)&zp[c4*4];
        a0 += wv[c4*4+0]*pv.x; a1 += wv[c4*4+1]*pv.y;
        a0 += wv[c4*4+2]*pv.z; a1 += wv[c4*4+3]*pv.w;
      }
      float v = sigm(bconst + a0 + a1);
      if (g == 0) rz[j]   = v*zp[j];
      else        ubuf[j] = v;
    }
    __syncthreads();
    if (g == 2){
      float a0 = 0.f, a1 = 0.f;
      #pragma unroll
      for (int c4 = 0; c4 < 16; ++c4){
        float4 rv = *(const float4*)&rz[c4*4];
        a0 += wv[c4*4+0]*rv.x; a1 += wv[c4*4+1]*rv.y;
        a0 += wv[c4*4+2]*rv.z; a1 += wv[c4*4+3]*rv.w;
      }
      float cc = tanhf(bconst + a0 + a1);
      float u  = ubuf[j];
      float zt = (1.0f - u)*zp[j] + u*cc;
      zs[(size_t)s*4096 + t*64 + j] = zt;
      zp[j] = zt;
    }
    __syncthreads();
  }
}

// ---------------- host launch ----------------
extern "C" void kernel_launch(void* const* d_in, const int* in_sizes, int n_in,
                              void* d_out, int out_size, void* d_ws, size_t ws_size,
                              hipStream_t stream){
  static const int Vl[5] = {2048, 1024, 512, 256, 128};
  static const int El[5] = {12288, 6144, 3072, 1536, 768};
  static const int VO[4] = {0, 2048, 3072, 3584};
  static const int EO[4] = {0, 12288, 18432, 21504};

  const float* xin = (const float*)d_in[0];
  const int*   ei[4]; const float* ea[4];
  for (int l = 0; l < 4; ++l){ ei[l] = (const int*)d_in[1 + 2*l]; ea[l] = (const float*)d_in[2 + 2*l]; }
  const float* Psrc[8] = {(const float*)d_in[11], (const float*)d_in[12], (const float*)d_in[13], (const float*)d_in[14],
                          (const float*)d_in[15], (const float*)d_in[16], (const float*)d_in[17], (const float*)d_in[18]};
  const float* conv_w[4]   = {(const float*)d_in[19], (const float*)d_in[20], (const float*)d_in[21], (const float*)d_in[22]};
  const float* deconv_w[4] = {(const float*)d_in[23], (const float*)d_in[24], (const float*)d_in[25], (const float*)d_in[26]};
  const float* fce1_w = (const float*)d_in[27]; const float* fce1_b = (const float*)d_in[28];
  const float* fce2_w = (const float*)d_in[29]; const float* fce2_b = (const float*)d_in[30];
  const float* fcd3_w = (const float*)d_in[31]; const float* fcd3_b = (const float*)d_in[32];
  const float* fcd4_w = (const float*)d_in[33]; const float* fcd4_b = (const float*)d_in[34];
  const float* dom_Wih = (const float*)d_in[35]; const float* dom_Whh = (const float*)d_in[36];
  const float* dom_bih = (const float*)d_in[37]; const float* dom_bhh = (const float*)d_in[38];
  const float* dom_aggw = (const float*)d_in[39]; const float* dom_aggb = (const float*)d_in[40];
  const float* ini_Wih = (const float*)d_in[41]; const float* ini_Whh = (const float*)d_in[42];
  const float* ini_bih = (const float*)d_in[43]; const float* ini_bhh = (const float*)d_in[44];
  const float* ini_aggw = (const float*)d_in[45]; const float* ini_aggb = (const float*)d_in[46];
  const float* tr_Wr = (const float*)d_in[47]; const float* tr_br = (const float*)d_in[48];
  const float* tr_Wu = (const float*)d_in[49]; const float* tr_bu = (const float*)d_in[50];
  const float* tr_Wc = (const float*)d_in[51]; const float* tr_bc = (const float*)d_in[52];

  // ---- carve workspace ----
  char* wsp = (char*)d_ws;
  size_t off = 0;
  auto carve = [&](size_t bytes) -> void* {
    void* p = wsp + off;
    off = (off + bytes + 255) & ~(size_t)255;
    return p;
  };
  const size_t BUFCAP = (size_t)NB*2048*8*64;
  float* bufA = (float*)carve(BUFCAP*4);   // bufA+bufB together hold GI (S*T x 512 bf16) during latent phase
  float* bufB = (float*)carve(BUFCAP*4);
  void* webt = carve((size_t)NB*1024*1024*2 + 1024);
  float*  We = (float*)webt;
  ushort* xT = (ushort*)webt;
  ushort* WeTb = (ushort*)carve((size_t)1536*64*32*2 + 1024);
  ushort* embB2 = (ushort*)carve((size_t)1024*64*64*2);
  float* zD   = (float*)carve((size_t)NB*128*64*4);
  float* z0   = (float*)carve((size_t)NB*128*64*4);
  float* domWhhT = (float*)carve(12288*4);
  float* iniWhhT = (float*)carve(12288*4);
  float* domAggT = (float*)carve(4096*4);
  float* iniAggT = (float*)carve(4096*4);
  float* trWrT   = (float*)carve(8192*4);
  float* trWuT   = (float*)carve(8192*4);
  float* trWcT   = (float*)carve(8192*4);
  ushort* WihPad2 = (ushort*)carve(512*64*2);
  ushort* Wfce1b = (ushort*)carve(8192*2);
  ushort* Wfce2b = (ushort*)carve(8192*2);
  ushort* Wfcd3b = (ushort*)carve(8192*2);
  ushort* Wfcd4b = (ushort*)carve(8192*2);
  static const int PM[8] = {1024, 512, 256, 128, 256, 512, 1024, 2048};
  static const int PK[8] = {2048, 1024, 512, 256, 128, 256, 512, 1024};
  ushort* Pb[8];
  for (int i = 0; i < 8; ++i) Pb[i] = (ushort*)carve((size_t)PM[i]*PK[i]*2);
  int* deg_all    = (int*)carve(TOTV*4);
  int* cursor_all = (int*)carve(TOTV*4);
  int* rowptr_all = (int*)carve((TOTV + 4)*4);
  int* elist_all  = (int*)carve(TOTE*4);
  (void)ws_size; (void)in_sizes; (void)n_in; (void)out_size;

  // ---- fused weight prep (one dispatch) ----
  PrepTasks T;
  int nt = 0;
  auto addT = [&](const float* s, void* d, int R, int C, int ty){
    T.src[nt] = s; T.dst[nt] = d; T.R[nt] = R; T.C[nt] = C; T.type[nt] = ty; ++nt;
  };
  addT(dom_Whh, domWhhT, 192, 64, 0);
  addT(ini_Whh, iniWhhT, 192, 64, 0);
  addT(dom_aggw, domAggT, 64, 64, 0);
  addT(ini_aggw, iniAggT, 64, 64, 0);
  addT(tr_Wr, trWrT, 64, 128, 0);
  addT(tr_Wu, trWuT, 64, 128, 0);
  addT(tr_Wc, trWcT, 64, 128, 0);
  addT(dom_Wih, WihPad2, 256, 64, 1);
  addT(ini_Wih, WihPad2 + 256*64, 256, 64, 1);
  addT(fce1_w, Wfce1b, 128, 64, 2);
  addT(fce2_w, Wfce2b, 64, 128, 2);
  addT(fcd3_w, Wfcd3b, 128, 64, 2);
  addT(fcd4_w, Wfcd4b, 64, 128, 2);
  for (int i = 0; i < 8; ++i) addT(Psrc[i], Pb[i], PM[i], PK[i], 2);
  T.ntask = nt;
  T.blk0[0] = 0;
  for (int i = 0; i < nt; ++i) T.blk0[i+1] = T.blk0[i] + (T.R[i]*T.C[i] + 255)/256;
  prep_all<<<T.blk0[nt], 256, 0, stream>>>(T);

  // ---- parallel CSR build ----
  const int* dsts[4] = {ei[0] + El[0], ei[1] + El[1], ei[2] + El[2], ei[3] + El[3]};
  csr_zero<<<(TOTV + 255)/256, 256, 0, stream>>>(deg_all);
  csr_deg <<<(TOTE + 255)/256, 256, 0, stream>>>(dsts[0], dsts[1], dsts[2], dsts[3], deg_all);
  csr_scan<<<4, 1024, 0, stream>>>(deg_all, rowptr_all, cursor_all);
  csr_fill<<<(TOTE + 255)/256, 256, 0, stream>>>(dsts[0], dsts[1], dsts[2], dsts[3], cursor_all, elist_all);
  csr_sort<<<(TOTV + 255)/256, 256, 0, stream>>>(rowptr_all, elist_all);

  // ---- stage helpers ----
  auto gconv = [&](const float* in, float* out, int l, const float* Wb, int Ci, int Co){
    int CiCo = Ci*Co;
    int tot = El[l]*CiCo;
    edge_we_kernel<<<(tot + 255)/256, 256, 0, stream>>>(ea[l], Wb, We, El[l], CiCo);
    int nblk = NB*Vl[l];
    const int* rp = rowptr_all + VO[l] + l;
    const int* el = elist_all + EO[l];
    #define GCASE(CI,CO) if (Ci==CI && Co==CO) gconv2_kernel<CI,CO><<<nblk, 256, 0, stream>>>(in, We, ei[l], rp, el, out, Vl[l]);
    GCASE(1,8)  GCASE(8,16)  GCASE(16,8)  GCASE(8,1)
    #undef GCASE
  };
  auto gconv_m = [&](const float* in, float* out, int l, const float* Wb, int Ci, int Co){
    int S = NB*Vl[l];
    int CiP = (Ci < 32) ? 32 : Ci;
    if (Ci == 16)      xpose_bf16<16,32><<<S, 256, 0, stream>>>(in, xT);
    else if (Ci == 32) xpose_bf16<32,32><<<S, 256, 0, stream>>>(in, xT);
    else               xpose_bf16<64,64><<<S, 256, 0, stream>>>(in, xT);
    if (Ci == 16 && Co == 32)      edge_weT2<16,32,32><<<El[l], 256, 0, stream>>>(ea[l], Wb, WeTb);
    else if (Ci == 32 && Co == 64) edge_weT2<32,64,32><<<El[l], 256, 0, stream>>>(ea[l], Wb, WeTb);
    else if (Ci == 64 && Co == 32) edge_weT2<64,32,64><<<El[l], 256, 0, stream>>>(ea[l], Wb, WeTb);
    else if (Ci == 32 && Co == 16) edge_weT2<32,16,32><<<El[l], 256, 0, stream>>>(ea[l], Wb, WeTb);
    const int* rp = rowptr_all + VO[l] + l;
    const int* el = elist_all + EO[l];
    #define GMC(CIP,CO) if (CiP==CIP && Co==CO) gconv_mfma4<CIP,CO><<<S, 256, 0, stream>>>(xT, WeTb, ei[l], rp, el, out, Vl[l]);
    GMC(32,32) GMC(32,64) GMC(64,32) GMC(32,16)
    #undef GMC
  };
  auto pool2 = [&](int pi, const float* hin, float* out, int M, int K, int NN){
    dim3 g(NN/64, M/64, NB);
    pool_mfma64f<<<g, 256, 0, stream>>>(Pb[pi], hin, out, M, K, NN);
  };

  // ---- encoder ----
  gconv(xin,  bufA, 0, conv_w[0], 1, 8);
  pool2(0, bufA, bufB, 1024, 2048, 512);
  gconv(bufB, bufA, 1, conv_w[1], 8, 16);
  pool2(1, bufA, bufB, 512, 1024, 1024);
  gconv_m(bufB, bufA, 2, conv_w[2], 16, 32);
  pool2(2, bufA, bufB, 256, 512, 2048);
  gconv_m(bufB, bufA, 3, conv_w[3], 32, 64);
  pool2(3, bufA, bufB, 128, 256, 4096);

  // fused fce1+fce2: (s,64,t) fp32 -> emb (s,t,64) bf16 (ELU then tanh)
  pw2_mfma<64,128,64,1,2,0,1><<<1024, 256, 0, stream>>>(bufB, Wfce1b, fce1_b, Wfce2b, fce2_b, embB2);

  // ---- latent ----
  dim3 gg(8, 1024, 1);
  pool_mfma64<1><<<gg, 256, 0, stream>>>(embB2, WihPad2, (void*)bufA, 65536, 64, 512);
  gru3m_kernel<<<2*NB*128, 192, 0, stream>>>((const ushort*)bufA,
      domWhhT, iniWhhT, dom_bih, dom_bhh, domAggT, dom_aggb,
      ini_bih, ini_bhh, iniAggT, ini_aggb, zD, z0, NB*128);
  trans2_kernel<<<NB*128, 192, 0, stream>>>(z0, zD, trWrT, trWuT, trWcT, tr_br, tr_bu, tr_bc, bufA);

  // ---- decoder ----
  pw2_mfma<64,128,64,1,1,1,0><<<1024, 256, 0, stream>>>(bufA, Wfcd3b, fcd3_b, Wfcd4b, fcd4_b, bufB);
  pool2(4, bufB, bufA, 256, 128, 4096);
  gconv_m(bufA, bufB, 3, deconv_w[0], 64, 32);
  pool2(5, bufB, bufA, 512, 256, 2048);
  gconv_m(bufA, bufB, 2, deconv_w[1], 32, 16);
  pool2(6, bufB, bufA, 1024, 512, 1024);
  gconv(bufA, bufB, 1, deconv_w[2], 16, 8);
  pool2(7, bufB, bufA, 2048, 1024, 512);
  gconv(bufA, (float*)d_out, 0, deconv_w[3], 8, 1);
}

// Round 18
// 738.312 us; speedup vs baseline: 1.1002x; 1.0041x over previous
//
#include <hip/hip_runtime.h>

#define NB 8   // batch
#define TT 64  // time

typedef __attribute__((ext_vector_type(8))) short bf16x8_t;
typedef __attribute__((ext_vector_type(4))) float f32x4_t;

__device__ __forceinline__ float sigm(float x){ return 1.0f/(1.0f+expf(-x)); }
__device__ __forceinline__ float eluf(float x){ return x>0.0f ? x : expm1f(x); }
__device__ __forceinline__ ushort f2bf(float f){
  uint u = __float_as_uint(f);
  return (ushort)((u + 0x7FFFu + ((u >> 16) & 1u)) >> 16);   // RNE
}
__device__ __forceinline__ float bf2f(ushort u){
  return __uint_as_float(((uint)u) << 16);
}

// CSR fused-level geometry (levels 0..3)
__device__ __constant__ int c_VL[4] = {2048, 1024, 512, 256};
__device__ __constant__ int c_VO[4] = {0, 2048, 3072, 3584};
__device__ __constant__ int c_EO[4] = {0, 12288, 18432, 21504};
#define TOTV 3840
#define TOTE 23040

// ---------------- fused weight prep ----------------
#define NPREP 21
struct PrepTasks {
  const float* src[NPREP];
  void* dst[NPREP];
  int R[NPREP], C[NPREP];
  int type[NPREP];   // 0: fp32 transpose; 1: pad_wih; 2: bf16 convert
  int blk0[NPREP + 1];
  int ntask;
};

__global__ __launch_bounds__(256) void prep_all(PrepTasks T){
  int b = blockIdx.x;
  int t = 0;
  while (t + 1 < T.ntask && b >= T.blk0[t+1]) ++t;
  int idx = (b - T.blk0[t])*256 + threadIdx.x;
  int n = T.R[t]*T.C[t];
  if (idx >= n) return;
  int ty = T.type[t];
  if (ty == 0){
    int C = T.C[t];
    int r = idx / C, c = idx - r*C;
    ((float*)T.dst[t])[c*T.R[t] + r] = T.src[t][idx];
  } else if (ty == 1){
    int r = idx >> 6;
    ((ushort*)T.dst[t])[idx] = (r < 192) ? f2bf(T.src[t][idx]) : (ushort)0;
  } else {
    ((ushort*)T.dst[t])[idx] = f2bf(T.src[t][idx]);
  }
}

// ---------------- fused gconv prep: xpose (blocks [0,S)) + edge_weT2 (blocks [S,S+E)) ----------------
template<int Ci, int CiP, int Co>
__global__ __launch_bounds__(256) void gprep(
    const float* __restrict__ in, ushort* __restrict__ xT,
    const float* __restrict__ attr, const float* __restrict__ Wb,
    ushort* __restrict__ WeT, int S){
  __shared__ float lds[Ci*65];
  int tid = threadIdx.x;
  if ((int)blockIdx.x < S){
    // xpose: in (s, Ci, 64) fp32 -> xT (s, 64, CiP) bf16 (zero-pad ci >= Ci)
    float (*tile)[65] = (float(*)[65])lds;
    int s = blockIdx.x;
    const float* ip = in + (size_t)s*Ci*64;
    for (int i = tid; i < Ci*64; i += 256) tile[i>>6][i&63] = ip[i];
    __syncthreads();
    ushort* op = xT + (size_t)s*64*CiP;
    for (int i = tid; i < 64*CiP; i += 256){
      int t = i / CiP, ci = i - t*CiP;
      op[i] = (ci < Ci) ? f2bf(tile[ci][t]) : (ushort)0;
    }
  } else {
    // edge_weT2: spline expand -> WeT[e, co, ciP] bf16
    float (*s2)[Co + 1] = (float(*)[Co + 1])lds;
    int e = blockIdx.x - S;
    float f[3]; int i0[3];
    #pragma unroll
    for (int d = 0; d < 3; ++d){
      float p  = attr[e*3+d]*2.0f;
      float fl = fminf(fmaxf(floorf(p), 0.0f), 1.0f);
      i0[d] = (int)fl;
      f[d]  = p - fl;
    }
    float w[8]; int fl8[8];
    #pragma unroll
    for (int c0 = 0; c0 < 2; ++c0)
      #pragma unroll
      for (int c1 = 0; c1 < 2; ++c1)
        #pragma unroll
        for (int c2 = 0; c2 < 2; ++c2){
          int k = c0*4 + c1*2 + c2;
          w[k] = (c0 ? f[0] : 1.0f - f[0]) * (c1 ? f[1] : 1.0f - f[1]) * (c2 ? f[2] : 1.0f - f[2]);
          fl8[k] = (i0[0]+c0)*9 + (i0[1]+c1)*3 + (i0[2]+c2);
        }
    constexpr int CiCo = Ci*Co;
    for (int r = tid; r < CiCo; r += 256){
      float acc = 0.0f;
      #pragma unroll
      for (int k = 0; k < 8; ++k) acc += w[k]*Wb[fl8[k]*CiCo + r];
      s2[r/Co][r - (r/Co)*Co] = acc;
    }
    __syncthreads();
    ushort* op = WeT + (size_t)e*(Co*CiP);
    for (int r2 = tid; r2 < Co*CiP; r2 += 256){
      int co = r2 / CiP, ci = r2 - co*CiP;
      op[r2] = (ci < Ci) ? f2bf(s2[ci][co]) : (ushort)0;
    }
  }
}

// ---------------- parallel CSR build ----------------
__global__ void csr_zero(int* __restrict__ deg_all){
  int i = blockIdx.x*256 + threadIdx.x;
  if (i < TOTV) deg_all[i] = 0;
}

__global__ void csr_deg(const int* __restrict__ d0, const int* __restrict__ d1,
                        const int* __restrict__ d2, const int* __restrict__ d3,
                        int* __restrict__ deg_all){
  int idx = blockIdx.x*256 + threadIdx.x;
  if (idx >= TOTE) return;
  int l = (idx < 12288) ? 0 : (idx < 18432) ? 1 : (idx < 21504) ? 2 : 3;
  int e = idx - c_EO[l];
  const int* dl = (l==0)?d0:(l==1)?d1:(l==2)?d2:d3;
  atomicAdd(&deg_all[c_VO[l] + dl[e]], 1);
}

__global__ __launch_bounds__(1024) void csr_scan(const int* __restrict__ deg_all,
                                                 int* __restrict__ rowptr_all,
                                                 int* __restrict__ cursor_all){
  __shared__ int a[2048], b[2048];
  int l = blockIdx.x;
  int Vv = c_VL[l], vo = c_VO[l], eo = c_EO[l];
  int tid = threadIdx.x;
  for (int i = tid; i < 2048; i += 1024) a[i] = (i < Vv) ? deg_all[vo + i] : 0;
  __syncthreads();
  int* s = a; int* d = b;
  for (int off = 1; off < 2048; off <<= 1){
    for (int i = tid; i < 2048; i += 1024) d[i] = s[i] + ((i >= off) ? s[i-off] : 0);
    __syncthreads();
    int* t = s; s = d; d = t;
  }
  int rbase = vo + l;
  for (int i = tid; i < Vv; i += 1024){
    int excl = (i == 0) ? 0 : s[i-1];
    rowptr_all[rbase + i] = excl;
    cursor_all[vo + i]    = eo + excl;
  }
  if (tid == 0) rowptr_all[rbase + Vv] = s[2047];
}

__global__ void csr_fill(const int* __restrict__ d0, const int* __restrict__ d1,
                         const int* __restrict__ d2, const int* __restrict__ d3,
                         int* __restrict__ cursor_all, int* __restrict__ elist_all){
  int idx = blockIdx.x*256 + threadIdx.x;
  if (idx >= TOTE) return;
  int l = (idx < 12288) ? 0 : (idx < 18432) ? 1 : (idx < 21504) ? 2 : 3;
  int e = idx - c_EO[l];
  const int* dl = (l==0)?d0:(l==1)?d1:(l==2)?d2:d3;
  int p = atomicAdd(&cursor_all[c_VO[l] + dl[e]], 1);
  elist_all[p] = e;
}

__global__ void csr_sort(const int* __restrict__ rowptr_all, int* __restrict__ elist_all){
  int idx = blockIdx.x*256 + threadIdx.x;
  if (idx >= TOTV) return;
  int l = (idx < 2048) ? 0 : (idx < 3072) ? 1 : (idx < 3584) ? 2 : 3;
  int v = idx - c_VO[l];
  int rbase = c_VO[l] + l, eo = c_EO[l];
  int s = eo + rowptr_all[rbase + v], epos = eo + rowptr_all[rbase + v + 1];
  for (int i = s + 1; i < epos; ++i){
    int key = elist_all[i];
    int j = i - 1;
    while (j >= s && elist_all[j] > key){ elist_all[j+1] = elist_all[j]; --j; }
    elist_all[j+1] = key;
  }
}

// B-spline edge weights (fp32, vector gconv levels 0/1)
__global__ void edge_we_kernel(const float* __restrict__ attr, const float* __restrict__ Wb,
                               float* __restrict__ We, int E, int CiCo){
  int idx = blockIdx.x*256 + threadIdx.x;
  if (idx >= E*CiCo) return;
  int e = idx / CiCo, r = idx - e*CiCo;
  float f[3]; int i0[3];
  #pragma unroll
  for (int d = 0; d < 3; ++d){
    float p  = attr[e*3+d]*2.0f;
    float fl = fminf(fmaxf(floorf(p), 0.0f), 1.0f);
    i0[d] = (int)fl;
    f[d]  = p - fl;
  }
  float acc = 0.0f;
  #pragma unroll
  for (int c0 = 0; c0 < 2; ++c0){
    float w0 = c0 ? f[0] : 1.0f - f[0];
    #pragma unroll
    for (int c1 = 0; c1 < 2; ++c1){
      float w1 = c1 ? f[1] : 1.0f - f[1];
      #pragma unroll
      for (int c2 = 0; c2 < 2; ++c2){
        float w2 = c2 ? f[2] : 1.0f - f[2];
        int flat = (i0[0]+c0)*9 + (i0[1]+c1)*3 + (i0[2]+c2);
        acc += w0*w1*w2 * Wb[flat*CiCo + r];
      }
    }
  }
  We[idx] = acc;
}

// ---------------- graph conv (vector path, levels 0/1), es-table prefetch ----------------
template<int Ci, int Co>
__global__ __launch_bounds__(256) void gconv2_kernel(
    const float* __restrict__ x, const float* __restrict__ We,
    const int* __restrict__ src_arr, const int* __restrict__ rowptr,
    const int* __restrict__ elist, float* __restrict__ out, int V){
  constexpr int CiCo = Ci*Co;
  __shared__ float ws[4][CiCo];
  __shared__ float red[Co*64];
  __shared__ int2 es[64];
  int blk = blockIdx.x;
  int n = blk / V, v = blk - n*V;
  int tid = threadIdx.x;
  int w = tid >> 6, lane = tid & 63;
  int rs = rowptr[v], re = rowptr[v+1];
  int deg = re - rs;
  int cnt0 = (deg < 64) ? deg : 64;
  if (tid < cnt0){
    int e = elist[rs + tid];
    es[tid] = make_int2(e, src_arr[e]);
  }
  __syncthreads();
  float acc[Co];
  #pragma unroll
  for (int i = 0; i < Co; ++i) acc[i] = 0.0f;

  for (int q = w; q < deg; q += 4){
    int e, src;
    if (q < 64){ e = es[q].x; src = es[q].y; }
    else { e = elist[rs + q]; src = src_arr[e]; }
    const float* wsrc = We + (size_t)e*CiCo;
    #pragma unroll
    for (int i = lane; i < CiCo; i += 64) ws[w][i] = wsrc[i];
    __builtin_amdgcn_s_waitcnt(0);
    const float* xp = x + ((size_t)(n*V + src))*(Ci*64) + lane;
    #pragma unroll 4
    for (int ci = 0; ci < Ci; ++ci){
      float xv = xp[(size_t)ci*64];
      if constexpr (Co >= 4){
        #pragma unroll
        for (int co = 0; co < Co; co += 4){
          float4 wv = *(const float4*)&ws[w][ci*Co + co];
          acc[co+0] += wv.x*xv;
          acc[co+1] += wv.y*xv;
          acc[co+2] += wv.z*xv;
          acc[co+3] += wv.w*xv;
        }
      } else {
        #pragma unroll
        for (int co = 0; co < Co; ++co) acc[co] += ws[w][ci*Co + co]*xv;
      }
    }
  }

  if (w == 0){
    #pragma unroll
    for (int co = 0; co < Co; ++co) red[co*64 + lane] = acc[co];
  }
  __syncthreads();
  #pragma unroll
  for (int ww = 1; ww < 4; ++ww){
    if (w == ww){
      #pragma unroll
      for (int co = 0; co < Co; ++co) red[co*64 + lane] += acc[co];
    }
    __syncthreads();
  }
  float scale = 1.0f / fmaxf((float)deg, 1.0f);
  size_t ob = ((size_t)(n*V + v))*(Co*64);
  for (int co = w; co < Co; co += 4)
    out[ob + (size_t)co*64 + lane] = eluf(red[co*64 + lane]*scale);
}

// ---------------- graph conv (MFMA path, levels 2/3), wave-split edges ----------------
template<int CiP, int Co>
__global__ __launch_bounds__(256, 4) void gconv_mfma4(
    const ushort* __restrict__ xT, const ushort* __restrict__ WeT,
    const int* __restrict__ src_arr, const int* __restrict__ rowptr,
    const int* __restrict__ elist, float* __restrict__ out, int V){
  constexpr int MT = Co/16, KT = CiP/32;
  __shared__ int2 es[64];
  __shared__ float red[Co*64];
  int bid = blockIdx.x;
  int r8 = bid & 7, q0 = bid >> 3;
  int n = q0 & 7;
  int v = ((q0 >> 3) << 3) | r8;
  int tid = threadIdx.x;
  int w = tid >> 6, lane = tid & 63;
  int l15 = lane & 15, g = lane >> 4;
  int rs = rowptr[v], re = rowptr[v+1];
  int deg = re - rs;
  int cnt0 = (deg < 64) ? deg : 64;
  if (tid < cnt0){
    int e = elist[rs + tid];
    es[tid] = make_int2(e, src_arr[e]);
  }
  __syncthreads();
  f32x4_t acc[MT][4];
  #pragma unroll
  for (int m = 0; m < MT; ++m)
    #pragma unroll
    for (int tt = 0; tt < 4; ++tt) acc[m][tt] = (f32x4_t){0.f,0.f,0.f,0.f};
  for (int q = w; q < deg; q += 4){
    int e, src;
    if (q < 64){ e = es[q].x; src = es[q].y; }
    else { e = elist[rs + q]; src = src_arr[e]; }
    const ushort* xp = xT + ((size_t)(n*V + src))*(64*CiP) + (size_t)l15*CiP + g*8;
    const ushort* wp = WeT + (size_t)e*(Co*CiP) + (size_t)l15*CiP + g*8;
    #pragma unroll
    for (int kt = 0; kt < KT; ++kt){
      bf16x8_t bfrag[4];
      #pragma unroll
      for (int tt = 0; tt < 4; ++tt)
        bfrag[tt] = *(const bf16x8_t*)(xp + (size_t)tt*16*CiP + kt*32);
      #pragma unroll
      for (int m = 0; m < MT; ++m){
        bf16x8_t afrag = *(const bf16x8_t*)(wp + (size_t)m*16*CiP + kt*32);
        #pragma unroll
        for (int tt = 0; tt < 4; ++tt)
          acc[m][tt] = __builtin_amdgcn_mfma_f32_16x16x32_bf16(afrag, bfrag[tt], acc[m][tt], 0, 0, 0);
      }
    }
  }
  if (w == 0){
    #pragma unroll
    for (int m = 0; m < MT; ++m)
      #pragma unroll
      for (int tt = 0; tt < 4; ++tt)
        #pragma unroll
        for (int r = 0; r < 4; ++r)
          red[(m*16 + g*4 + r)*64 + tt*16 + l15] = acc[m][tt][r];
  }
  __syncthreads();
  #pragma unroll
  for (int ww = 1; ww < 4; ++ww){
    if (w == ww){
      #pragma unroll
      for (int m = 0; m < MT; ++m)
        #pragma unroll
        for (int tt = 0; tt < 4; ++tt)
          #pragma unroll
          for (int r = 0; r < 4; ++r)
            red[(m*16 + g*4 + r)*64 + tt*16 + l15] += acc[m][tt][r];
    }
    __syncthreads();
  }
  float scale = 1.0f / fmaxf((float)deg, 1.0f);
  size_t ob = ((size_t)(n*V + v))*(Co*64);
  for (int i = tid; i < Co*64; i += 256)
    out[ob + i] = eluf(red[i]*scale);
}

// ---------------- 64x64-tile MFMA GEMM, bf16 BT operand (GI GEMM only) ----------------
template<int OUTBF>
__global__ __launch_bounds__(256) void pool_mfma64(
    const ushort* __restrict__ A, const ushort* __restrict__ BT, void* __restrict__ Cout,
    int M, int K, int NN){
  __shared__ ushort As[64*40];
  __shared__ ushort Bs[64*40];
  char* Asb = (char*)As; char* Bsb = (char*)Bs;
  int tid = threadIdx.x;
  int wv = tid >> 6, lane = tid & 63;
  int g = lane >> 4, l15 = lane & 15;
  int wr = wv >> 1, wc = wv & 1;
  int m0 = blockIdx.y*64, n0 = blockIdx.x*64;
  const ushort* Bp = BT + (size_t)blockIdx.z*((size_t)NN*K);
  f32x4_t acc[2][2];
  #pragma unroll
  for (int i = 0; i < 2; ++i)
    #pragma unroll
    for (int j = 0; j < 2; ++j) acc[i][j] = (f32x4_t){0.f,0.f,0.f,0.f};
  int srow = tid >> 2, slot = tid & 3;
  int wbo = srow*80 + slot*16;
  const ushort* gA = A  + (size_t)(m0+srow)*K + slot*8;
  const ushort* gB = Bp + (size_t)(n0+srow)*K + slot*8;
  for (int k0 = 0; k0 < K; k0 += 32){
    uint4 va = *(const uint4*)(gA + k0);
    uint4 vb = *(const uint4*)(gB + k0);
    __syncthreads();
    *(uint4*)(Asb + wbo) = va;
    *(uint4*)(Bsb + wbo) = vb;
    __syncthreads();
    bf16x8_t af[2], bfr[2];
    #pragma unroll
    for (int f = 0; f < 2; ++f){
      af[f]  = *(const bf16x8_t*)(Asb + (wr*32 + f*16 + l15)*80 + g*16);
      bfr[f] = *(const bf16x8_t*)(Bsb + (wc*32 + f*16 + l15)*80 + g*16);
    }
    #pragma unroll
    for (int fm = 0; fm < 2; ++fm)
      #pragma unroll
      for (int fn = 0; fn < 2; ++fn)
        acc[fm][fn] = __builtin_amdgcn_mfma_f32_16x16x32_bf16(af[fm], bfr[fn], acc[fm][fn], 0, 0, 0);
  }
  #pragma unroll
  for (int fm = 0; fm < 2; ++fm){
    int row = m0 + wr*32 + fm*16 + g*4;
    #pragma unroll
    for (int fn = 0; fn < 2; ++fn){
      int col = n0 + wc*32 + fn*16 + l15;
      if constexpr (OUTBF){
        ushort* Cb = (ushort*)Cout + (size_t)blockIdx.z*((size_t)M*NN);
        #pragma unroll
        for (int r = 0; r < 4; ++r)
          Cb[(size_t)(row + r)*NN + col] = f2bf(acc[fm][fn][r]);
      } else {
        float* Cf = (float*)Cout + (size_t)blockIdx.z*((size_t)M*NN);
        #pragma unroll
        for (int r = 0; r < 4; ++r)
          Cf[(size_t)(row + r)*NN + col] = acc[fm][fn][r];
      }
    }
  }
}

// ---------------- 64x64-tile MFMA GEMM, fp32 B in (K,NN) layout (pools; fused transpose) ----------------
__global__ __launch_bounds__(256) void pool_mfma64f(
    const ushort* __restrict__ A, const float* __restrict__ B, float* __restrict__ Cout,
    int M, int K, int NN){
  __shared__ ushort As[64*40];
  __shared__ ushort Bs[64*40];
  char* Asb = (char*)As; char* Bsb = (char*)Bs;
  int tid = threadIdx.x;
  int wv = tid >> 6, lane = tid & 63;
  int g = lane >> 4, l15 = lane & 15;
  int wr = wv >> 1, wc = wv & 1;
  int m0 = blockIdx.y*64, n0 = blockIdx.x*64;
  const float* Bp = B + (size_t)blockIdx.z*((size_t)K*NN);
  float* Cp = Cout + (size_t)blockIdx.z*((size_t)M*NN);
  f32x4_t acc[2][2];
  #pragma unroll
  for (int i = 0; i < 2; ++i)
    #pragma unroll
    for (int j = 0; j < 2; ++j) acc[i][j] = (f32x4_t){0.f,0.f,0.f,0.f};
  int srow = tid >> 2, slot = tid & 3;
  int wboA = srow*80 + slot*16;
  const ushort* gA = A + (size_t)(m0+srow)*K + slot*8;
  int bcol = tid & 63, bkg = tid >> 6;
  const float* gB = Bp + n0 + bcol;
  int wboB = bcol*80 + bkg*16;
  for (int k0 = 0; k0 < K; k0 += 32){
    uint4 va = *(const uint4*)(gA + k0);
    ushort bv[8];
    #pragma unroll
    for (int kk = 0; kk < 8; ++kk)
      bv[kk] = f2bf(gB[(size_t)(k0 + bkg*8 + kk)*NN]);
    __syncthreads();
    *(uint4*)(Asb + wboA) = va;
    *(uint4*)(Bsb + wboB) = *(uint4*)bv;
    __syncthreads();
    bf16x8_t af[2], bfr[2];
    #pragma unroll
    for (int f = 0; f < 2; ++f){
      af[f]  = *(const bf16x8_t*)(Asb + (wr*32 + f*16 + l15)*80 + g*16);
      bfr[f] = *(const bf16x8_t*)(Bsb + (wc*32 + f*16 + l15)*80 + g*16);
    }
    #pragma unroll
    for (int fm = 0; fm < 2; ++fm)
      #pragma unroll
      for (int fn = 0; fn < 2; ++fn)
        acc[fm][fn] = __builtin_amdgcn_mfma_f32_16x16x32_bf16(af[fm], bfr[fn], acc[fm][fn], 0, 0, 0);
  }
  #pragma unroll
  for (int fm = 0; fm < 2; ++fm){
    int row = m0 + wr*32 + fm*16 + g*4;
    #pragma unroll
    for (int fn = 0; fn < 2; ++fn){
      int col = n0 + wc*32 + fn*16 + l15;
      #pragma unroll
      for (int r = 0; r < 4; ++r)
        Cp[(size_t)(row + r)*NN + col] = acc[fm][fn][r];
    }
  }
}

// ---------------- fused dual MFMA pointwise ----------------
template<int C, int O1, int O2, int ACT1, int ACT2, int INF, int OUTF>
__global__ __launch_bounds__(256) void pw2_mfma(
    const void* __restrict__ inv,
    const ushort* __restrict__ W1, const float* __restrict__ b1,
    const ushort* __restrict__ W2, const float* __restrict__ b2,
    void* __restrict__ outv){
  constexpr int CP = C + 8, O1P = O1 + 8;
  constexpr int MT1 = O1/16, KT1 = C/32;
  constexpr int MT2 = O2/16, KT2 = O1/32;
  __shared__ ushort XT[64*CP];
  __shared__ ushort YT[64*O1P];
  int s = blockIdx.x, tid = threadIdx.x;
  int w = tid >> 6, lane = tid & 63;
  int l15 = lane & 15, g = lane >> 4;
  if constexpr (INF == 0){
    const float* ip = (const float*)inv + (size_t)s*C*64;
    for (int i = tid; i < C*64; i += 256){ int c = i >> 6, t = i & 63; XT[t*CP + c] = f2bf(ip[i]); }
  } else {
    const float* ip = (const float*)inv + (size_t)s*64*C;
    for (int i = tid; i < C*64; i += 256){ int t = i / C, c = i - t*C; XT[t*CP + c] = f2bf(ip[i]); }
  }
  __syncthreads();
  int trow = w*16 + l15;
  {
    f32x4_t acc[MT1];
    #pragma unroll
    for (int m = 0; m < MT1; ++m) acc[m] = (f32x4_t){0.f,0.f,0.f,0.f};
    #pragma unroll
    for (int kt = 0; kt < KT1; ++kt){
      bf16x8_t bfrag = *(const bf16x8_t*)(&XT[trow*CP + kt*32 + g*8]);
      #pragma unroll
      for (int m = 0; m < MT1; ++m){
        bf16x8_t afrag = *(const bf16x8_t*)(W1 + (size_t)(m*16 + l15)*C + kt*32 + g*8);
        acc[m] = __builtin_amdgcn_mfma_f32_16x16x32_bf16(afrag, bfrag, acc[m], 0, 0, 0);
      }
    }
    #pragma unroll
    for (int m = 0; m < MT1; ++m){
      #pragma unroll
      for (int r = 0; r < 4; ++r){
        int o = m*16 + g*4 + r;
        float v = acc[m][r] + b1[o];
        v = (ACT1 == 1) ? eluf(v) : tanhf(v);
        YT[trow*O1P + o] = f2bf(v);
      }
    }
  }
  __syncthreads();
  {
    f32x4_t acc[MT2];
    #pragma unroll
    for (int m = 0; m < MT2; ++m) acc[m] = (f32x4_t){0.f,0.f,0.f,0.f};
    #pragma unroll
    for (int kt = 0; kt < KT2; ++kt){
      bf16x8_t bfrag = *(const bf16x8_t*)(&YT[trow*O1P + kt*32 + g*8]);
      #pragma unroll
      for (int m = 0; m < MT2; ++m){
        bf16x8_t afrag = *(const bf16x8_t*)(W2 + (size_t)(m*16 + l15)*O1 + kt*32 + g*8);
        acc[m] = __builtin_amdgcn_mfma_f32_16x16x32_bf16(afrag, bfrag, acc[m], 0, 0, 0);
      }
    }
    if constexpr (OUTF == 0){
      float* op = (float*)outv + (size_t)s*O2*64;
      #pragma unroll
      for (int m = 0; m < MT2; ++m){
        #pragma unroll
        for (int r = 0; r < 4; ++r){
          int o = m*16 + g*4 + r;
          float v = acc[m][r] + b2[o];
          v = (ACT2 == 1) ? eluf(v) : tanhf(v);
          op[(size_t)o*64 + trow] = v;
        }
      }
    } else {
      constexpr int O2P = O2 + 8;
      #pragma unroll
      for (int m = 0; m < MT2; ++m){
        #pragma unroll
        for (int r = 0; r < 4; ++r){
          int o = m*16 + g*4 + r;
          float v = acc[m][r] + b2[o];
          v = (ACT2 == 1) ? eluf(v) : tanhf(v);
          XT[trow*O2P + o] = f2bf(v);
        }
      }
      __syncthreads();
      ushort* op = (ushort*)outv + (size_t)s*64*O2;
      for (int i = tid; i < 64*O2; i += 256){
        int t = i / O2, o = i - t*O2;
        op[i] = XT[t*O2P + o];
      }
    }
  }
}

// ---------------- merged GRU scans (dom + ini), gate-per-wave; GI stride 512 ----------------
__global__ __launch_bounds__(192) void gru3m_kernel(
    const ushort* __restrict__ GI,
    const float* __restrict__ WhhT_d, const float* __restrict__ WhhT_i,
    const float* __restrict__ bih_d, const float* __restrict__ bhh_d,
    const float* __restrict__ aggT_d, const float* __restrict__ aggb_d,
    const float* __restrict__ bih_i, const float* __restrict__ bhh_i,
    const float* __restrict__ aggT_i, const float* __restrict__ aggb_i,
    float* __restrict__ zD, float* __restrict__ z0, int S){
  __shared__ float hsh[64];
  __shared__ float rbuf[64];
  __shared__ float zbuf[64];
  int bid = blockIdx.x;
  bool dom = (bid < S);
  int s = dom ? bid : bid - S;
  int TS = dom ? 64 : 16;
  const float* WhhT  = dom ? WhhT_d : WhhT_i;
  const float* bih   = dom ? bih_d  : bih_i;
  const float* bhh   = dom ? bhh_d  : bhh_i;
  const float* aggT  = dom ? aggT_d : aggT_i;
  const float* aggb  = dom ? aggb_d : aggb_i;
  float* zout        = dom ? zD     : z0;
  int tid = threadIdx.x;
  int g = tid >> 6, j = tid & 63;
  if (tid < 64) hsh[tid] = 0.0f;
  float whh[64];
  #pragma unroll
  for (int c = 0; c < 64; ++c) whh[c] = WhhT[c*192 + tid];
  float b_i = bih[tid], b_h = bhh[tid];
  const ushort* gp = GI + (size_t)s*64*512 + (dom ? 0 : 256) + tid;
  float gi_cur = b_i + bf2f(gp[0]);
  __syncthreads();
  for (int t = 0; t < TS; ++t){
    ushort gnx = (t + 1 < TS) ? gp[(size_t)(t+1)*512] : (ushort)0;
    float gh0 = 0.f, gh1 = 0.f;
    #pragma unroll
    for (int c4 = 0; c4 < 16; ++c4){
      float4 hv = *(const float4*)&hsh[c4*4];
      gh0 += whh[c4*4+0]*hv.x; gh1 += whh[c4*4+1]*hv.y;
      gh0 += whh[c4*4+2]*hv.z; gh1 += whh[c4*4+3]*hv.w;
    }
    float gh = b_h + gh0 + gh1;
    if (g == 0)      rbuf[j] = sigm(gi_cur + gh);
    else if (g == 1) zbuf[j] = sigm(gi_cur + gh);
    __syncthreads();
    if (g == 2){
      float gg = tanhf(gi_cur + rbuf[j]*gh);
      float z  = zbuf[j];
      hsh[j] = (1.0f - z)*gg + z*hsh[j];
    }
    __syncthreads();
    gi_cur = b_i + bf2f(gnx);
  }
  if (tid < 64){
    float a = aggb[tid];
    #pragma unroll
    for (int c = 0; c < 64; ++c) a += aggT[c*64 + tid]*hsh[c];
    zout[(size_t)s*64 + tid] = tanhf(a);
  }
}

// ---------------- transition: gate-per-wave, register weights ----------------
__global__ __launch_bounds__(192) void trans2_kernel(
    const float* __restrict__ z0, const float* __restrict__ zD,
    const float* __restrict__ WrT, const float* __restrict__ WuT, const float* __restrict__ WcT,
    const float* __restrict__ br, const float* __restrict__ bu, const float* __restrict__ bc,
    float* __restrict__ zs){
  __shared__ float zp[64];
  __shared__ float zd[64];
  __shared__ float rz[64];
  __shared__ float ubuf[64];
  int s = blockIdx.x, tid = threadIdx.x;
  int g = tid >> 6, j = tid & 63;
  if (tid < 64){ zp[tid] = z0[(size_t)s*64 + tid]; zd[tid] = zD[(size_t)s*64 + tid]; }
  const float* WT = (g == 0) ? WrT : (g == 1) ? WuT : WcT;
  const float* bb = (g == 0) ? br  : (g == 1) ? bu  : bc;
  float wv[64];
  #pragma unroll
  for (int c = 0; c < 64; ++c) wv[c] = WT[c*64 + j];
  float bconst = bb[j];
  __syncthreads();
  {
    float a0 = 0.f, a1 = 0.f;
    #pragma unroll
    for (int c4 = 0; c4 < 16; ++c4){
      float4 dv = *(const float4*)&zd[c4*4];
      a0 += WT[(64 + c4*4 + 0)*64 + j]*dv.x;
      a1 += WT[(64 + c4*4 + 1)*64 + j]*dv.y;
      a0 += WT[(64 + c4*4 + 2)*64 + j]*dv.z;
      a1 += WT[(64 + c4*4 + 3)*64 + j]*dv.w;
    }
    bconst += a0 + a1;
  }
  for (int t = 0; t < 64; ++t){
    if (g < 2){
      float a0 = 0.f, a1 = 0.f;
      #pragma unroll
      for (int c4 = 0; c4 < 16; ++c4){
        float4 pv = *(const float4*)&zp[c4*4];
        a0 += wv[c4*4+0]*pv.x; a1 += wv[c4*4+1]*pv.y;
        a0 += wv[c4*4+2]*pv.z; a1 += wv[c4*4+3]*pv.w;
      }
      float v = sigm(bconst + a0 + a1);
      if (g == 0) rz[j]   = v*zp[j];
      else        ubuf[j] = v;
    }
    __syncthreads();
    if (g == 2){
      float a0 = 0.f, a1 = 0.f;
      #pragma unroll
      for (int c4 = 0; c4 < 16; ++c4){
        float4 rv = *(const float4*)&rz[c4*4];
        a0 += wv[c4*4+0]*rv.x; a1 += wv[c4*4+1]*rv.y;
        a0 += wv[c4*4+2]*rv.z; a1 += wv[c4*4+3]*rv.w;
      }
      float cc = tanhf(bconst + a0 + a1);
      float u  = ubuf[j];
      float zt = (1.0f - u)*zp[j] + u*cc;
      zs[(size_t)s*4096 + t*64 + j] = zt;
      zp[j] = zt;
    }
    __syncthreads();
  }
}

// ---------------- host launch ----------------
extern "C" void kernel_launch(void* const* d_in, const int* in_sizes, int n_in,
                              void* d_out, int out_size, void* d_ws, size_t ws_size,
                              hipStream_t stream){
  static const int Vl[5] = {2048, 1024, 512, 256, 128};
  static const int El[5] = {12288, 6144, 3072, 1536, 768};
  static const int VO[4] = {0, 2048, 3072, 3584};
  static const int EO[4] = {0, 12288, 18432, 21504};

  const float* xin = (const float*)d_in[0];
  const int*   ei[4]; const float* ea[4];
  for (int l = 0; l < 4; ++l){ ei[l] = (const int*)d_in[1 + 2*l]; ea[l] = (const float*)d_in[2 + 2*l]; }
  const float* Psrc[8] = {(const float*)d_in[11], (const float*)d_in[12], (const float*)d_in[13], (const float*)d_in[14],
                          (const float*)d_in[15], (const float*)d_in[16], (const float*)d_in[17], (const float*)d_in[18]};
  const float* conv_w[4]   = {(const float*)d_in[19], (const float*)d_in[20], (const float*)d_in[21], (const float*)d_in[22]};
  const float* deconv_w[4] = {(const float*)d_in[23], (const float*)d_in[24], (const float*)d_in[25], (const float*)d_in[26]};
  const float* fce1_w = (const float*)d_in[27]; const float* fce1_b = (const float*)d_in[28];
  const float* fce2_w = (const float*)d_in[29]; const float* fce2_b = (const float*)d_in[30];
  const float* fcd3_w = (const float*)d_in[31]; const float* fcd3_b = (const float*)d_in[32];
  const float* fcd4_w = (const float*)d_in[33]; const float* fcd4_b = (const float*)d_in[34];
  const float* dom_Wih = (const float*)d_in[35]; const float* dom_Whh = (const float*)d_in[36];
  const float* dom_bih = (const float*)d_in[37]; const float* dom_bhh = (const float*)d_in[38];
  const float* dom_aggw = (const float*)d_in[39]; const float* dom_aggb = (const float*)d_in[40];
  const float* ini_Wih = (const float*)d_in[41]; const float* ini_Whh = (const float*)d_in[42];
  const float* ini_bih = (const float*)d_in[43]; const float* ini_bhh = (const float*)d_in[44];
  const float* ini_aggw = (const float*)d_in[45]; const float* ini_aggb = (const float*)d_in[46];
  const float* tr_Wr = (const float*)d_in[47]; const float* tr_br = (const float*)d_in[48];
  const float* tr_Wu = (const float*)d_in[49]; const float* tr_bu = (const float*)d_in[50];
  const float* tr_Wc = (const float*)d_in[51]; const float* tr_bc = (const float*)d_in[52];

  // ---- carve workspace ----
  char* wsp = (char*)d_ws;
  size_t off = 0;
  auto carve = [&](size_t bytes) -> void* {
    void* p = wsp + off;
    off = (off + bytes + 255) & ~(size_t)255;
    return p;
  };
  const size_t BUFCAP = (size_t)NB*2048*8*64;
  float* bufA = (float*)carve(BUFCAP*4);
  float* bufB = (float*)carve(BUFCAP*4);
  void* webt = carve((size_t)NB*1024*1024*2 + 1024);
  float*  We = (float*)webt;
  ushort* xT = (ushort*)webt;
  ushort* WeTb = (ushort*)carve((size_t)1536*64*32*2 + 1024);
  ushort* embB2 = (ushort*)carve((size_t)1024*64*64*2);
  float* zD   = (float*)carve((size_t)NB*128*64*4);
  float* z0   = (float*)carve((size_t)NB*128*64*4);
  float* domWhhT = (float*)carve(12288*4);
  float* iniWhhT = (float*)carve(12288*4);
  float* domAggT = (float*)carve(4096*4);
  float* iniAggT = (float*)carve(4096*4);
  float* trWrT   = (float*)carve(8192*4);
  float* trWuT   = (float*)carve(8192*4);
  float* trWcT   = (float*)carve(8192*4);
  ushort* WihPad2 = (ushort*)carve(512*64*2);
  ushort* Wfce1b = (ushort*)carve(8192*2);
  ushort* Wfce2b = (ushort*)carve(8192*2);
  ushort* Wfcd3b = (ushort*)carve(8192*2);
  ushort* Wfcd4b = (ushort*)carve(8192*2);
  static const int PM[8] = {1024, 512, 256, 128, 256, 512, 1024, 2048};
  static const int PK[8] = {2048, 1024, 512, 256, 128, 256, 512, 1024};
  ushort* Pb[8];
  for (int i = 0; i < 8; ++i) Pb[i] = (ushort*)carve((size_t)PM[i]*PK[i]*2);
  int* deg_all    = (int*)carve(TOTV*4);
  int* cursor_all = (int*)carve(TOTV*4);
  int* rowptr_all = (int*)carve((TOTV + 4)*4);
  int* elist_all  = (int*)carve(TOTE*4);
  (void)ws_size; (void)in_sizes; (void)n_in; (void)out_size;

  // ---- fused weight prep (one dispatch) ----
  PrepTasks T;
  int nt = 0;
  auto addT = [&](const float* s, void* d, int R, int C, int ty){
    T.src[nt] = s; T.dst[nt] = d; T.R[nt] = R; T.C[nt] = C; T.type[nt] = ty; ++nt;
  };
  addT(dom_Whh, domWhhT, 192, 64, 0);
  addT(ini_Whh, iniWhhT, 192, 64, 0);
  addT(dom_aggw, domAggT, 64, 64, 0);
  addT(ini_aggw, iniAggT, 64, 64, 0);
  addT(tr_Wr, trWrT, 64, 128, 0);
  addT(tr_Wu, trWuT, 64, 128, 0);
  addT(tr_Wc, trWcT, 64, 128, 0);
  addT(dom_Wih, WihPad2, 256, 64, 1);
  addT(ini_Wih, WihPad2 + 256*64, 256, 64, 1);
  addT(fce1_w, Wfce1b, 128, 64, 2);
  addT(fce2_w, Wfce2b, 64, 128, 2);
  addT(fcd3_w, Wfcd3b, 128, 64, 2);
  addT(fcd4_w, Wfcd4b, 64, 128, 2);
  for (int i = 0; i < 8; ++i) addT(Psrc[i], Pb[i], PM[i], PK[i], 2);
  T.ntask = nt;
  T.blk0[0] = 0;
  for (int i = 0; i < nt; ++i) T.blk0[i+1] = T.blk0[i] + (T.R[i]*T.C[i] + 255)/256;
  prep_all<<<T.blk0[nt], 256, 0, stream>>>(T);

  // ---- parallel CSR build ----
  const int* dsts[4] = {ei[0] + El[0], ei[1] + El[1], ei[2] + El[2], ei[3] + El[3]};
  csr_zero<<<(TOTV + 255)/256, 256, 0, stream>>>(deg_all);
  csr_deg <<<(TOTE + 255)/256, 256, 0, stream>>>(dsts[0], dsts[1], dsts[2], dsts[3], deg_all);
  csr_scan<<<4, 1024, 0, stream>>>(deg_all, rowptr_all, cursor_all);
  csr_fill<<<(TOTE + 255)/256, 256, 0, stream>>>(dsts[0], dsts[1], dsts[2], dsts[3], cursor_all, elist_all);
  csr_sort<<<(TOTV + 255)/256, 256, 0, stream>>>(rowptr_all, elist_all);

  // ---- stage helpers ----
  auto gconv = [&](const float* in, float* out, int l, const float* Wb, int Ci, int Co){
    int CiCo = Ci*Co;
    int tot = El[l]*CiCo;
    edge_we_kernel<<<(tot + 255)/256, 256, 0, stream>>>(ea[l], Wb, We, El[l], CiCo);
    int nblk = NB*Vl[l];
    const int* rp = rowptr_all + VO[l] + l;
    const int* el = elist_all + EO[l];
    #define GCASE(CI,CO) if (Ci==CI && Co==CO) gconv2_kernel<CI,CO><<<nblk, 256, 0, stream>>>(in, We, ei[l], rp, el, out, Vl[l]);
    GCASE(1,8)  GCASE(8,16)  GCASE(16,8)  GCASE(8,1)
    #undef GCASE
  };
  auto gconv_m = [&](const float* in, float* out, int l, const float* Wb, int Ci, int Co){
    int S = NB*Vl[l];
    const int* rp = rowptr_all + VO[l] + l;
    const int* el = elist_all + EO[l];
    if (Ci == 16 && Co == 32){
      gprep<16,32,32><<<S + El[l], 256, 0, stream>>>(in, xT, ea[l], Wb, WeTb, S);
      gconv_mfma4<32,32><<<S, 256, 0, stream>>>(xT, WeTb, ei[l], rp, el, out, Vl[l]);
    } else if (Ci == 32 && Co == 64){
      gprep<32,32,64><<<S + El[l], 256, 0, stream>>>(in, xT, ea[l], Wb, WeTb, S);
      gconv_mfma4<32,64><<<S, 256, 0, stream>>>(xT, WeTb, ei[l], rp, el, out, Vl[l]);
    } else if (Ci == 64 && Co == 32){
      gprep<64,64,32><<<S + El[l], 256, 0, stream>>>(in, xT, ea[l], Wb, WeTb, S);
      gconv_mfma4<64,32><<<S, 256, 0, stream>>>(xT, WeTb, ei[l], rp, el, out, Vl[l]);
    } else if (Ci == 32 && Co == 16){
      gprep<32,32,16><<<S + El[l], 256, 0, stream>>>(in, xT, ea[l], Wb, WeTb, S);
      gconv_mfma4<32,16><<<S, 256, 0, stream>>>(xT, WeTb, ei[l], rp, el, out, Vl[l]);
    }
  };
  auto pool2 = [&](int pi, const float* hin, float* out, int M, int K, int NN){
    dim3 g(NN/64, M/64, NB);
    pool_mfma64f<<<g, 256, 0, stream>>>(Pb[pi], hin, out, M, K, NN);
  };

  // ---- encoder ----
  gconv(xin,  bufA, 0, conv_w[0], 1, 8);
  pool2(0, bufA, bufB, 1024, 2048, 512);
  gconv(bufB, bufA, 1, conv_w[1], 8, 16);
  pool2(1, bufA, bufB, 512, 1024, 1024);
  gconv_m(bufB, bufA, 2, conv_w[2], 16, 32);
  pool2(2, bufA, bufB, 256, 512, 2048);
  gconv_m(bufB, bufA, 3, conv_w[3], 32, 64);
  pool2(3, bufA, bufB, 128, 256, 4096);

  // fused fce1+fce2: (s,64,t) fp32 -> emb (s,t,64) bf16 (ELU then tanh)
  pw2_mfma<64,128,64,1,2,0,1><<<1024, 256, 0, stream>>>(bufB, Wfce1b, fce1_b, Wfce2b, fce2_b, embB2);

  // ---- latent ----
  dim3 gg(8, 1024, 1);
  pool_mfma64<1><<<gg, 256, 0, stream>>>(embB2, WihPad2, (void*)bufA, 65536, 64, 512);
  gru3m_kernel<<<2*NB*128, 192, 0, stream>>>((const ushort*)bufA,
      domWhhT, iniWhhT, dom_bih, dom_bhh, domAggT, dom_aggb,
      ini_bih, ini_bhh, iniAggT, ini_aggb, zD, z0, NB*128);
  trans2_kernel<<<NB*128, 192, 0, stream>>>(z0, zD, trWrT, trWuT, trWcT, tr_br, tr_bu, tr_bc, bufA);

  // ---- decoder ----
  pw2_mfma<64,128,64,1,1,1,0><<<1024, 256, 0, stream>>>(bufA, Wfcd3b, fcd3_b, Wfcd4b, fcd4_b, bufB);
  pool2(4, bufB, bufA, 256, 128, 4096);
  gconv_m(bufA, bufB, 3, deconv_w[0], 64, 32);
  pool2(5, bufB, bufA, 512, 256, 2048);
  gconv_m(bufA, bufB, 2, deconv_w[1], 32, 16);
  pool2(6, bufB, bufA, 1024, 512, 1024);
  gconv(bufA, bufB, 1, deconv_w[2], 16, 8);
  pool2(7, bufB, bufA, 2048, 1024, 512);
  gconv(bufA, (float*)d_out, 0, deconv_w[3], 8, 1);
}